// Round 16
// baseline (356.206 us; speedup 1.0000x reference)
//
#include <hip/hip_runtime.h>
#include <math.h>

#define BATCH 4
#define NN 2048
#define DD 256
#define HH 2048
#define DP 64
#define KTOP 16

typedef float f32x4 __attribute__((ext_vector_type(4)));
typedef short short8 __attribute__((ext_vector_type(8)));
typedef short short4v __attribute__((ext_vector_type(4)));

__device__ __forceinline__ short f2bf(float x) {
    union { float f; unsigned u; } v; v.f = x;
    unsigned r = v.u + 0x7FFFu + ((v.u >> 16) & 1u);   // round-to-nearest-even
    return (short)(r >> 16);
}
__device__ __forceinline__ float bf2f(short s) {
    union { unsigned u; float f; } v; v.u = ((unsigned)(unsigned short)s) << 16;
    return v.f;
}

// ---------------- Head: fused proj (blocks 0..511, Q/K -> 3-comp bf16) + weight prep ----------------
__global__ __launch_bounds__(256) void head_kernel(
    const float* __restrict__ act,
    const float* __restrict__ Wq, const float* __restrict__ bq,
    const float* __restrict__ Wk, const float* __restrict__ bk,
    const float* __restrict__ Wc, const float* __restrict__ bc,
    const float* __restrict__ W2h, const float* __restrict__ Wfh,
    short* __restrict__ Qh, short* __restrict__ Qm, short* __restrict__ Ql,
    short* __restrict__ Kh, short* __restrict__ Km, short* __restrict__ Kl,
    short* __restrict__ Pno,
    short* __restrict__ W2hT_hi, short* __restrict__ W2hT_lo,
    short* __restrict__ WfhT_hi, short* __restrict__ WfhT_lo)
{
    __shared__ float smem[16 * 256];   // 16 KB, aliased by both parts

    if (blockIdx.x < 512) {
        // ---- proj: rows row0 .. row0+15 ----
        float (*rowbuf)[256] = (float(*)[256])smem;
        const int row0 = blockIdx.x * 16;
        const int t = threadIdx.x;
        const int wave = t >> 6, lane = t & 63;
        const float* src = act + (size_t)row0 * DD;
        for (int i = t; i < 16 * DD; i += 256) rowbuf[i >> 8][i & 255] = src[i];
        __syncthreads();

        float q[4], k[4], c[4];
        #pragma unroll
        for (int r = 0; r < 4; ++r) { q[r] = bq[lane]; k[r] = bk[lane]; c[r] = bc[lane]; }

        for (int d = 0; d < DD; ++d) {
            float wq = Wq[d * DP + lane];
            float wk = Wk[d * DP + lane];
            float wc = Wc[d * DP + lane];
            #pragma unroll
            for (int r = 0; r < 4; ++r) {
                float av = rowbuf[wave * 4 + r][d];
                q[r] = fmaf(av, wq, q[r]);
                k[r] = fmaf(av, wk, k[r]);
                c[r] = fmaf(av, wc, c[r]);
            }
        }
        #pragma unroll
        for (int r = 0; r < 4; ++r) {
            float ss = c[r] * c[r];
            #pragma unroll
            for (int off = 32; off; off >>= 1) ss += __shfl_xor(ss, off);
            float nrm = fmaxf(sqrtf(ss), 1e-12f);
            size_t o = (size_t)(row0 + wave * 4 + r) * DP + lane;
            // 3-way bf16 split (~24 mantissa bits): v ~= hi + mid + lo
            short h1 = f2bf(q[r]); float rs = q[r] - bf2f(h1);
            short m1 = f2bf(rs);   rs -= bf2f(m1);
            Qh[o] = h1; Qm[o] = m1; Ql[o] = f2bf(rs);
            h1 = f2bf(k[r]); rs = k[r] - bf2f(h1);
            m1 = f2bf(rs);   rs -= bf2f(m1);
            Kh[o] = h1; Km[o] = m1; Kl[o] = f2bf(rs);
            Pno[o] = f2bf(c[r] / nrm);
        }
    } else {
        // ---- prep: transpose + hi/lo split ----
        float (*tile)[33] = (float(*)[33])smem;
        int b = blockIdx.x - 512;
        const float* src; short *dhi, *dlo; int R, C, r0, c0;
        if (b < 512) {               // W2h [256][2048] -> W2hT [2048][256]
            src = W2h; dhi = W2hT_hi; dlo = W2hT_lo; R = 256; C = 2048;
            r0 = (b >> 6) * 32; c0 = (b & 63) * 32;
        } else {                     // Wfh [2048][256] -> WfhT [256][2048]
            b -= 512;
            src = Wfh; dhi = WfhT_hi; dlo = WfhT_lo; R = 2048; C = 256;
            r0 = (b >> 3) * 32; c0 = (b & 7) * 32;
        }
        int tx = threadIdx.x & 31, ty = threadIdx.x >> 5;
        #pragma unroll
        for (int i = 0; i < 4; ++i)
            tile[ty + 8 * i][tx] = src[(size_t)(r0 + ty + 8 * i) * C + c0 + tx];
        __syncthreads();
        #pragma unroll
        for (int i = 0; i < 4; ++i) {
            float v = tile[tx][ty + 8 * i];
            short hi = f2bf(v);
            size_t o = (size_t)(c0 + ty + 8 * i) * R + r0 + tx;
            dhi[o] = hi;
            dlo[o] = f2bf(v - bf2f(hi));
        }
    }
}

// ---------------- Stage 2 (MFMA, 1-barrier): scores -> scbuf -> tournament + softmax + gather -----
// grid: 1024 blocks (8 q-rows each), 512 threads (8 waves).
// Phase 1: wave w computes 16 independent 16x16 score tiles (cols m0=(tt*8+w)*16) with 12 MFMAs
// (6-term bf16^3, round-13-verified mapping: C row = lg*4+j = A-row(l&15), C col = lr = B-row),
// split over 2 parallel acc chains; K frags read straight from L2. Writes rows 0..7 to scbuf.
// Phase 2 (after ONE barrier): wave w = row; loads 2048 scores (32 ds_read_b32) and runs the
// proven round-12 tournament/softmax/gather unchanged.
__global__ __launch_bounds__(512) void attn_fused_kernel(
    const short* __restrict__ Qh, const short* __restrict__ Qm, const short* __restrict__ Ql,
    const short* __restrict__ Kh, const short* __restrict__ Km, const short* __restrict__ Kl,
    const float* __restrict__ log_temp,
    const float* __restrict__ states, float* __restrict__ incoming)
{
    const int t = threadIdx.x;
    const int w = t >> 6, l = t & 63;
    const int lr = l & 15, lg = l >> 4;
    const int row0 = blockIdx.x * 8;
    const int b = row0 >> 11;
    const int row = row0 + w;

    __shared__ float scbuf[8][2048];   // 64 KB

    const float temp = fminf(fmaxf(expf(log_temp[0]), 0.1f), 10.0f);
    const float scale = 1.0f / (8.0f * temp);   // SCALE = sqrt(64) = 8

    // A fragments: Q rows row0 + (lr&7) (rows 8..15 duplicate; their C rows are discarded)
    const size_t qoff = (size_t)(row0 + (lr & 7)) * DP;
    short8 ah[2], am[2], al[2];
    #pragma unroll
    for (int ks = 0; ks < 2; ++ks) {
        const size_t qa = qoff + ks * 32 + lg * 8;
        ah[ks] = *(const short8*)(Qh + qa);
        am[ks] = *(const short8*)(Qm + qa);
        al[ks] = *(const short8*)(Ql + qa);
    }

    const size_t kbase = (size_t)b * NN * DP;

    for (int tt = 0; tt < 16; ++tt) {
        const int m0 = (tt * 8 + w) * 16;
        const size_t koff = kbase + (size_t)(m0 + lr) * DP;
        f32x4 accA = (f32x4){0.f, 0.f, 0.f, 0.f};
        f32x4 accB = (f32x4){0.f, 0.f, 0.f, 0.f};
        #pragma unroll
        for (int ks = 0; ks < 2; ++ks) {
            const size_t ka = koff + ks * 32 + lg * 8;
            short8 bh = *(const short8*)(Kh + ka);
            short8 bm = *(const short8*)(Km + ka);
            short8 bl = *(const short8*)(Kl + ka);
            accA = __builtin_amdgcn_mfma_f32_16x16x32_bf16(ah[ks], bh, accA, 0, 0, 0);
            accB = __builtin_amdgcn_mfma_f32_16x16x32_bf16(ah[ks], bm, accB, 0, 0, 0);
            accA = __builtin_amdgcn_mfma_f32_16x16x32_bf16(am[ks], bh, accA, 0, 0, 0);
            accB = __builtin_amdgcn_mfma_f32_16x16x32_bf16(ah[ks], bl, accB, 0, 0, 0);
            accA = __builtin_amdgcn_mfma_f32_16x16x32_bf16(al[ks], bh, accA, 0, 0, 0);
            accB = __builtin_amdgcn_mfma_f32_16x16x32_bf16(am[ks], bm, accB, 0, 0, 0);
        }
        if (lg < 2) {
            #pragma unroll
            for (int j = 0; j < 4; ++j)
                scbuf[lg * 4 + j][m0 + lr] = (accA[j] + accB[j]) * scale;
        }
    }
    __syncthreads();   // the ONE barrier

    // phase 2: load this wave's row; slot s of lane l holds m = (s>>1)*128 + (s&1)*64 + l
    float sc[32];
    #pragma unroll
    for (int s = 0; s < 32; ++s)
        sc[s] = scbuf[w][(s >> 1) * 128 + (s & 1) * 64 + l];

    // per-wave top-16 tournament (proven round-12 code, unchanged)
    float wv = 0.f; int wm = 0;
    for (int it = 0; it < KTOP; ++it) {
        float bv = sc[0]; int bs = 0;
        #pragma unroll
        for (int i = 1; i < 32; ++i) {
            bool g = sc[i] > bv;            // strict > keeps earliest slot (smallest m)
            bv = g ? sc[i] : bv;
            bs = g ? i : bs;
        }
        int bm = (bs >> 1) * 128 + (bs & 1) * 64 + l;
        #pragma unroll
        for (int off = 1; off < 64; off <<= 1) {
            float ov = __shfl_xor(bv, off);
            int   om = __shfl_xor(bm, off);
            bool take = (ov > bv) || (ov == bv && om < bm);
            bv = take ? ov : bv;
            bm = take ? om : bm;
        }
        if (l == it) { wv = bv; wm = bm; }
        if ((bm & 63) == l) {
            int s = ((bm >> 7) << 1) | ((bm >> 6) & 1);
            #pragma unroll
            for (int i = 0; i < 32; ++i) if (s == i) sc[i] = -3.0e38f;
        }
    }

    // softmax over the 16 winners (lanes 0..15 hold them, descending)
    float mx = __shfl(wv, 0);
    float e = (l < KTOP) ? expf(wv - mx) : 0.f;
    float Z = e;
    #pragma unroll
    for (int off = 1; off < 64; off <<= 1) Z += __shfl_xor(Z, off);
    float wnorm = e / Z;

    // fused gather: incoming[row] = sum_k w_k * states[b, idx_k]
    const float* Sb = states + (size_t)b * NN * DD;
    f32x4 acc = (f32x4){0.f, 0.f, 0.f, 0.f};
    #pragma unroll
    for (int kk = 0; kk < KTOP; ++kk) {
        float wk = __shfl(wnorm, kk);
        int   ik = __shfl(wm, kk);
        const float4 v = *(const float4*)(Sb + (size_t)ik * DD + l * 4);
        acc[0] = fmaf(wk, v.x, acc[0]);
        acc[1] = fmaf(wk, v.y, acc[1]);
        acc[2] = fmaf(wk, v.z, acc[2]);
        acc[3] = fmaf(wk, v.w, acc[3]);
    }
    *(float4*)(incoming + (size_t)row * DD + l * 4) = *(float4*)&acc;
}

// ---------------- Stage 3 (MFMA): sim -> sigmoid -> normalize -> combined -> mixed ----------------
__global__ __launch_bounds__(256) void coal_kernel(
    const short* __restrict__ pnb_g, const float* __restrict__ incoming,
    const float* __restrict__ temp_coal, float* __restrict__ mixed)
{
    const int b  = blockIdx.x >> 7;
    const int rem = blockIdx.x & 127;
    const int n0 = (rem >> 1) * 32;
    const int dh = rem & 1;
    const int t = threadIdx.x;
    const int w = t >> 6;
    const int l = t & 63;

    __shared__ alignas(16) short pnA[32][72];
    __shared__ alignas(16) short pnB[64][72];
    __shared__ alignas(16) short cwt[32][72];
    __shared__ alignas(16) short incT[128][72];
    __shared__ float rowsum[32];

    const size_t bbase = (size_t)b * NN;

    {
        int r = t >> 3, k8 = (t & 7) * 8;
        *(short8*)&pnA[r][k8] = *(const short8*)(pnb_g + (bbase + n0 + r) * DP + k8);
    }
    if (t < 32) rowsum[t] = 0.0f;

    const float tc = temp_coal[0];

    f32x4 acc[2][2];
    #pragma unroll
    for (int i = 0; i < 2; ++i)
        #pragma unroll
        for (int j = 0; j < 2; ++j)
            acc[i][j] = (f32x4){0.f, 0.f, 0.f, 0.f};

    const int lrow = l & 15;
    const int lk   = (l >> 4) * 8;

    for (int ch = 0; ch < 32; ++ch) {
        const int m0 = ch * 64;
        __syncthreads();

        {
            int r = t >> 2, kq = (t & 3) * 16;
            const short* src = pnb_g + (bbase + m0 + r) * DP + kq;
            *(short8*)&pnB[r][kq]     = *(const short8*)src;
            *(short8*)&pnB[r][kq + 8] = *(const short8*)(src + 8);
        }
        {
            int d4 = t & 31;
            int mg = t >> 5;
            const float* incb = incoming + (bbase + m0) * DD + dh * 128 + d4 * 4;
            #pragma unroll
            for (int i = 0; i < 8; ++i) {
                int m = mg * 8 + i;
                float4 v = *(const float4*)(incb + (size_t)m * DD);
                int db = d4 * 4;
                incT[db + 0][m] = f2bf(v.x);
                incT[db + 1][m] = f2bf(v.y);
                incT[db + 2][m] = f2bf(v.z);
                incT[db + 3][m] = f2bf(v.w);
            }
        }
        __syncthreads();

        f32x4 sacc[2];
        sacc[0] = (f32x4){0.f, 0.f, 0.f, 0.f};
        sacc[1] = (f32x4){0.f, 0.f, 0.f, 0.f};
        #pragma unroll
        for (int ks = 0; ks < 2; ++ks) {
            short8 bfr = *(const short8*)&pnB[w * 16 + lrow][lk + ks * 32];
            short8 a0  = *(const short8*)&pnA[lrow][lk + ks * 32];
            short8 a1  = *(const short8*)&pnA[16 + lrow][lk + ks * 32];
            sacc[0] = __builtin_amdgcn_mfma_f32_16x16x32_bf16(a0, bfr, sacc[0], 0, 0, 0);
            sacc[1] = __builtin_amdgcn_mfma_f32_16x16x32_bf16(a1, bfr, sacc[1], 0, 0, 0);
        }
        #pragma unroll
        for (int rt = 0; rt < 2; ++rt) {
            #pragma unroll
            for (int j = 0; j < 4; ++j) {
                int rr = rt * 16 + (l >> 4) * 4 + j;
                int cc = w * 16 + lrow;
                float cv = 1.0f / (1.0f + expf(-(sacc[rt][j] - 0.7f) * tc));
                cwt[rr][cc] = f2bf(cv);
            }
        }
        __syncthreads();

        {
            int r = t >> 3, c8 = (t & 7) * 8;
            short8 cv = *(const short8*)&cwt[r][c8];
            float p = 0.f;
            #pragma unroll
            for (int j = 0; j < 8; ++j) p += bf2f(cv[j]);
            p += __shfl_xor(p, 1);
            p += __shfl_xor(p, 2);
            p += __shfl_xor(p, 4);
            if ((t & 7) == 0) rowsum[r] += p;
        }

        #pragma unroll
        for (int ks = 0; ks < 2; ++ks) {
            short8 a0 = *(const short8*)&cwt[lrow][lk + ks * 32];
            short8 a1 = *(const short8*)&cwt[16 + lrow][lk + ks * 32];
            #pragma unroll
            for (int ct = 0; ct < 2; ++ct) {
                short8 bfr = *(const short8*)&incT[w * 32 + ct * 16 + lrow][lk + ks * 32];
                acc[0][ct] = __builtin_amdgcn_mfma_f32_16x16x32_bf16(a0, bfr, acc[0][ct], 0, 0, 0);
                acc[1][ct] = __builtin_amdgcn_mfma_f32_16x16x32_bf16(a1, bfr, acc[1][ct], 0, 0, 0);
            }
        }
    }
    __syncthreads();

    #pragma unroll
    for (int rt = 0; rt < 2; ++rt) {
        #pragma unroll
        for (int ct = 0; ct < 2; ++ct) {
            #pragma unroll
            for (int j = 0; j < 4; ++j) {
                int rr = rt * 16 + (l >> 4) * 4 + j;
                int cc = w * 32 + ct * 16 + lrow;
                float inv = 1.0f / (rowsum[rr] + 1e-8f);
                float comb = acc[rt][ct][j] * inv;
                size_t gi = (bbase + n0 + rr) * DD + dh * 128 + cc;
                mixed[gi] = 0.8f * incoming[gi] + 0.2f * comb;
            }
        }
    }
}

// ---------------- Stage 4a (MFMA): z = mixed@W2h + b2h -> q bits only ----------------
__global__ __launch_bounds__(256) void hdcA_kernel(
    const float* __restrict__ mixed,
    const short* __restrict__ W2hT_hi, const short* __restrict__ W2hT_lo,
    const float* __restrict__ b2h,
    unsigned short* __restrict__ qbits)
{
    const int rb = blockIdx.x >> 3;
    const int hs = blockIdx.x & 7;
    const int row0 = rb * 32;
    const int hbase = hs * 256;
    const int t = threadIdx.x;
    const int w = t >> 6, l = t & 63;
    const int lr = l & 15, lg = l >> 4;

    __shared__ short Ahi[32][264], Alo[32][264];
    __shared__ short Whi[64][136], Wlo[64][136];

    #pragma unroll
    for (int i = 0; i < 8; ++i) {
        int idx = t + i * 256;
        int r = idx >> 6, c = (idx & 63) * 4;
        float4 v = *(const float4*)(mixed + (size_t)(row0 + r) * DD + c);
        short4v hi4, lo4;
        hi4[0] = f2bf(v.x); lo4[0] = f2bf(v.x - bf2f(hi4[0]));
        hi4[1] = f2bf(v.y); lo4[1] = f2bf(v.y - bf2f(hi4[1]));
        hi4[2] = f2bf(v.z); lo4[2] = f2bf(v.z - bf2f(hi4[2]));
        hi4[3] = f2bf(v.w); lo4[3] = f2bf(v.w - bf2f(hi4[3]));
        *(short4v*)&Ahi[r][c] = hi4;
        *(short4v*)&Alo[r][c] = lo4;
    }

    for (int ch = 0; ch < 4; ++ch) {
        const int h0 = hbase + ch * 64;
        f32x4 zac[2];
        zac[0] = (f32x4){0.f, 0.f, 0.f, 0.f};
        zac[1] = (f32x4){0.f, 0.f, 0.f, 0.f};
        #pragma unroll
        for (int ks = 0; ks < 2; ++ks) {
            const int k0 = ks * 128;
            __syncthreads();
            {
                int r = t >> 2, cb = (t & 3) * 32;
                const short* sh = W2hT_hi + (size_t)(h0 + r) * DD + k0 + cb;
                const short* sl = W2hT_lo + (size_t)(h0 + r) * DD + k0 + cb;
                #pragma unroll
                for (int j = 0; j < 4; ++j) {
                    *(short8*)&Whi[r][cb + j * 8] = *(const short8*)(sh + j * 8);
                    *(short8*)&Wlo[r][cb + j * 8] = *(const short8*)(sl + j * 8);
                }
            }
            __syncthreads();
            #pragma unroll
            for (int kt = 0; kt < 4; ++kt) {
                int kk = k0 + kt * 32 + lg * 8;
                int kw = kt * 32 + lg * 8;
                short8 bhi = *(const short8*)&Whi[w * 16 + lr][kw];
                short8 blo = *(const short8*)&Wlo[w * 16 + lr][kw];
                #pragma unroll
                for (int mt = 0; mt < 2; ++mt) {
                    short8 ahi = *(const short8*)&Ahi[mt * 16 + lr][kk];
                    short8 alo = *(const short8*)&Alo[mt * 16 + lr][kk];
                    zac[mt] = __builtin_amdgcn_mfma_f32_16x16x32_bf16(ahi, bhi, zac[mt], 0, 0, 0);
                    zac[mt] = __builtin_amdgcn_mfma_f32_16x16x32_bf16(ahi, blo, zac[mt], 0, 0, 0);
                    zac[mt] = __builtin_amdgcn_mfma_f32_16x16x32_bf16(alo, bhi, zac[mt], 0, 0, 0);
                }
            }
        }
        const float bv = b2h[h0 + w * 16 + lr];
        #pragma unroll
        for (int mt = 0; mt < 2; ++mt) {
            #pragma unroll
            for (int j = 0; j < 4; ++j) {
                float z = zac[mt][j] + bv;
                unsigned long long bal = __ballot(z >= 0.0f);
                if (lr == 0)
                    qbits[(size_t)(row0 + mt * 16 + lg * 4 + j) * 128 + (h0 >> 4) + w] =
                        (unsigned short)((bal >> (lg * 16)) & 0xFFFFull);
            }
        }
    }
}

// ---------------- Stage 4b (MFMA): nm recompute + num/ns + strength + recall + out ----------------
__global__ __launch_bounds__(512) void hdcB_kernel(
    const float* __restrict__ mem, const unsigned short* __restrict__ qbits,
    const float* __restrict__ pos_codes, const int* __restrict__ step,
    const short* __restrict__ WfhT_hi,
    const float* __restrict__ bfh, const float* __restrict__ keys,
    const float* __restrict__ mixed, float* __restrict__ out)
{
    const int mb = blockIdx.x >> 1, nb = blockIdx.x & 1;
    const int row0 = mb * 32, d0 = nb * 128;
    const int t = threadIdx.x;
    const int w = t >> 6, l = t & 63;
    const int wm = w >> 2, wn = w & 3;
    const int lr = l & 15, lg = l >> 4;

    __shared__ short Ahi[32][72], Alo[32][72];
    __shared__ short Bhi[128][72];
    __shared__ float sred[32][2];
    __shared__ float strenL[32];

    int st = ((step[0] % 256) + 256) % 256;
    const float* pos = pos_codes + (size_t)st * HH;

    f32x4 acc[2];
    acc[0] = (f32x4){0.f, 0.f, 0.f, 0.f};
    acc[1] = (f32x4){0.f, 0.f, 0.f, 0.f};
    float pnum = 0.f, pns = 0.f;

    const int ar = t >> 4;              // row 0..31
    const int ah = (t & 15) * 4;        // h offset within 64-chunk
    const int arow = row0 + ar;
    const size_t memb = (size_t)arow * HH;
    const size_t keyb = (size_t)(arow & (NN - 1)) * HH;

    for (int kc = 0; kc < 32; ++kc) {
        const int h0 = kc * 64;
        __syncthreads();
        {   // A stage: nm recompute + num/ns partials (coalesced float4 loads)
            float4 mv = *(const float4*)(mem + memb + h0 + ah);
            float4 kv = *(const float4*)(keys + keyb + h0 + ah);
            float4 pv = *(const float4*)(pos + h0 + ah);
            unsigned bits = (unsigned)qbits[(size_t)arow * 128 + ((h0 + ah) >> 4)] >> (ah & 15);
            float mvs[4] = { mv.x, mv.y, mv.z, mv.w };
            float kvs[4] = { kv.x, kv.y, kv.z, kv.w };
            float pvs[4] = { pv.x, pv.y, pv.z, pv.w };
            short4v hi4, lo4;
            #pragma unroll
            for (int j = 0; j < 4; ++j) {
                float q = ((bits >> j) & 1u) ? 1.0f : -1.0f;
                float nmv = fmaf(0.05f * q, pvs[j], 0.95f * mvs[j]);
                pnum = fmaf(nmv, q * kvs[j], pnum);
                pns  = fmaf(nmv, nmv, pns);
                hi4[j] = f2bf(nmv);
                lo4[j] = f2bf(nmv - bf2f(hi4[j]));
            }
            *(short4v*)&Ahi[ar][ah] = hi4;
            *(short4v*)&Alo[ar][ah] = lo4;
        }
        {   // B stage: WfhT 128 x 64 (hi only)
            int r = t >> 2, hb = (t & 3) * 16;
            const short* sh = WfhT_hi + (size_t)(d0 + r) * HH + h0 + hb;
            *(short8*)&Bhi[r][hb]     = *(const short8*)sh;
            *(short8*)&Bhi[r][hb + 8] = *(const short8*)(sh + 8);
        }
        __syncthreads();
        #pragma unroll
        for (int kt = 0; kt < 2; ++kt) {
            const int kk = kt * 32 + lg * 8;
            short8 ahi = *(const short8*)&Ahi[wm * 16 + lr][kk];
            short8 alo = *(const short8*)&Alo[wm * 16 + lr][kk];
            #pragma unroll
            for (int nt = 0; nt < 2; ++nt) {
                short8 bhi = *(const short8*)&Bhi[wn * 32 + nt * 16 + lr][kk];
                acc[nt] = __builtin_amdgcn_mfma_f32_16x16x32_bf16(ahi, bhi, acc[nt], 0, 0, 0);
                acc[nt] = __builtin_amdgcn_mfma_f32_16x16x32_bf16(alo, bhi, acc[nt], 0, 0, 0);
            }
        }
    }

    // num/ns: reduce across the 16 threads sharing each row (same wave)
    #pragma unroll
    for (int off = 1; off < 16; off <<= 1) {
        pnum += __shfl_xor(pnum, off);
        pns  += __shfl_xor(pns, off);
    }
    if ((t & 15) == 0) { sred[ar][0] = pnum; sred[ar][1] = pns; }
    __syncthreads();
    if (t < 32) {
        float cosv = sred[t][0] / (fmaxf(sqrtf(sred[t][1]), 1e-8f) * sqrtf(2048.0f));
        strenL[t] = 1.0f / (1.0f + expf(-cosv));
    }
    __syncthreads();

    #pragma unroll
    for (int nt = 0; nt < 2; ++nt) {
        #pragma unroll
        for (int j = 0; j < 4; ++j) {
            int rloc = wm * 16 + lg * 4 + j;
            int col = d0 + wn * 32 + nt * 16 + lr;
            size_t gi = (size_t)(row0 + rloc) * DD + col;
            out[gi] = mixed[gi] + (acc[nt][j] + bfh[col]) * strenL[rloc];
        }
    }
}

extern "C" void kernel_launch(void* const* d_in, const int* in_sizes, int n_in,
                              void* d_out, int out_size, void* d_ws, size_t ws_size,
                              hipStream_t stream) {
    const float* states    = (const float*)d_in[0];
    const float* actions   = (const float*)d_in[1];
    const float* mem       = (const float*)d_in[2];
    const float* Wq        = (const float*)d_in[3];
    const float* bq        = (const float*)d_in[4];
    const float* Wk        = (const float*)d_in[5];
    const float* bk        = (const float*)d_in[6];
    const float* log_temp  = (const float*)d_in[7];
    const float* Wc        = (const float*)d_in[8];
    const float* bc        = (const float*)d_in[9];
    const float* temp_coal = (const float*)d_in[10];
    const float* W2h       = (const float*)d_in[11];
    const float* b2h       = (const float*)d_in[12];
    const float* Wfh       = (const float*)d_in[13];
    const float* bfh       = (const float*)d_in[14];
    const float* keys      = (const float*)d_in[15];
    const float* pos_codes = (const float*)d_in[16];
    const int*   step      = (const int*)d_in[17];
    float* out = (float*)d_out;

    float* ws = (float*)d_ws;
    float* mixed    = ws;                                    // 2,097,152 f32  (8 MB)
    short* W2hT_hi  = (short*)(mixed + 2097152);             // 524288 shorts
    short* W2hT_lo  = W2hT_hi + 524288;
    short* WfhT_hi  = W2hT_lo + 524288;
    short* WfhT_lo  = WfhT_hi + 524288;
    short* Qh       = WfhT_lo + 524288;                      // 6 x 524288 shorts (Q/K comps)
    short* Qm       = Qh + 524288;
    short* Ql       = Qm + 524288;
    short* Kh       = Ql + 524288;
    short* Km       = Kh + 524288;
    short* Kl       = Km + 524288;
    float* incoming = (float*)(Kl + 524288);                 // 2,097,152 f32
    short* pn_bf    = (short*)(incoming + 2097152);          // 524288 shorts
    // qbits aliases the Q-comp region (dead after attn; hdcA runs later on the same stream)
    unsigned short* qbits = (unsigned short*)Qh;             // 1,048,576 u16 (2 MB <= 3 MB)

    head_kernel<<<1536, 256, 0, stream>>>(actions, Wq, bq, Wk, bk, Wc, bc, W2h, Wfh,
                                          Qh, Qm, Ql, Kh, Km, Kl, pn_bf,
                                          W2hT_hi, W2hT_lo, WfhT_hi, WfhT_lo);
    attn_fused_kernel<<<BATCH * NN / 8, 512, 0, stream>>>(Qh, Qm, Ql, Kh, Km, Kl,
                                                          log_temp, states, incoming);
    coal_kernel<<<BATCH * (NN / 32) * 2, 256, 0, stream>>>(pn_bf, incoming, temp_coal, mixed);
    hdcA_kernel<<<(BATCH * NN / 32) * 8, 256, 0, stream>>>(mixed, W2hT_hi, W2hT_lo, b2h, qbits);
    hdcB_kernel<<<(BATCH * NN / 32) * 2, 512, 0, stream>>>(mem, qbits, pos_codes, step,
                                                           WfhT_hi, bfh, keys, mixed, out);
}

// Round 17
// 332.001 us; speedup vs baseline: 1.0729x; 1.0729x over previous
//
#include <hip/hip_runtime.h>
#include <math.h>

#define BATCH 4
#define NN 2048
#define DD 256
#define HH 2048
#define DP 64
#define KTOP 16

typedef float f32x4 __attribute__((ext_vector_type(4)));
typedef short short8 __attribute__((ext_vector_type(8)));
typedef short short4v __attribute__((ext_vector_type(4)));

__device__ __forceinline__ short f2bf(float x) {
    union { float f; unsigned u; } v; v.f = x;
    unsigned r = v.u + 0x7FFFu + ((v.u >> 16) & 1u);   // round-to-nearest-even
    return (short)(r >> 16);
}
__device__ __forceinline__ float bf2f(short s) {
    union { unsigned u; float f; } v; v.u = ((unsigned)(unsigned short)s) << 16;
    return v.f;
}

// ---------------- Head: fused proj (blocks 0..511) + weight prep (blocks 512..1535) ----------------
__global__ __launch_bounds__(256) void head_kernel(
    const float* __restrict__ act,
    const float* __restrict__ Wq, const float* __restrict__ bq,
    const float* __restrict__ Wk, const float* __restrict__ bk,
    const float* __restrict__ Wc, const float* __restrict__ bc,
    const float* __restrict__ W2h, const float* __restrict__ Wfh,
    float* __restrict__ Qo, float* __restrict__ Ko, short* __restrict__ Pno,
    short* __restrict__ W2hT_hi, short* __restrict__ W2hT_lo,
    short* __restrict__ WfhT_hi, short* __restrict__ WfhT_lo)
{
    __shared__ float smem[16 * 256];   // 16 KB, aliased by both parts

    if (blockIdx.x < 512) {
        // ---- proj: rows row0 .. row0+15 ----
        float (*rowbuf)[256] = (float(*)[256])smem;
        const int row0 = blockIdx.x * 16;
        const int t = threadIdx.x;
        const int wave = t >> 6, lane = t & 63;
        const float* src = act + (size_t)row0 * DD;
        for (int i = t; i < 16 * DD; i += 256) rowbuf[i >> 8][i & 255] = src[i];
        __syncthreads();

        float q[4], k[4], c[4];
        #pragma unroll
        for (int r = 0; r < 4; ++r) { q[r] = bq[lane]; k[r] = bk[lane]; c[r] = bc[lane]; }

        for (int d = 0; d < DD; ++d) {
            float wq = Wq[d * DP + lane];
            float wk = Wk[d * DP + lane];
            float wc = Wc[d * DP + lane];
            #pragma unroll
            for (int r = 0; r < 4; ++r) {
                float av = rowbuf[wave * 4 + r][d];
                q[r] = fmaf(av, wq, q[r]);
                k[r] = fmaf(av, wk, k[r]);
                c[r] = fmaf(av, wc, c[r]);
            }
        }
        #pragma unroll
        for (int r = 0; r < 4; ++r) {
            float ss = c[r] * c[r];
            #pragma unroll
            for (int off = 32; off; off >>= 1) ss += __shfl_xor(ss, off);
            float nrm = fmaxf(sqrtf(ss), 1e-12f);
            size_t o = (size_t)(row0 + wave * 4 + r) * DP + lane;
            Qo[o] = q[r];
            Ko[o] = k[r];
            Pno[o] = f2bf(c[r] / nrm);
        }
    } else {
        // ---- prep: transpose + hi/lo split ----
        float (*tile)[33] = (float(*)[33])smem;
        int b = blockIdx.x - 512;
        const float* src; short *dhi, *dlo; int R, C, r0, c0;
        if (b < 512) {               // W2h [256][2048] -> W2hT [2048][256]
            src = W2h; dhi = W2hT_hi; dlo = W2hT_lo; R = 256; C = 2048;
            r0 = (b >> 6) * 32; c0 = (b & 63) * 32;
        } else {                     // Wfh [2048][256] -> WfhT [256][2048]
            b -= 512;
            src = Wfh; dhi = WfhT_hi; dlo = WfhT_lo; R = 2048; C = 256;
            r0 = (b >> 3) * 32; c0 = (b & 7) * 32;
        }
        int tx = threadIdx.x & 31, ty = threadIdx.x >> 5;
        #pragma unroll
        for (int i = 0; i < 4; ++i)
            tile[ty + 8 * i][tx] = src[(size_t)(r0 + ty + 8 * i) * C + c0 + tx];
        __syncthreads();
        #pragma unroll
        for (int i = 0; i < 4; ++i) {
            float v = tile[tx][ty + 8 * i];
            short hi = f2bf(v);
            size_t o = (size_t)(c0 + ty + 8 * i) * R + r0 + tx;
            dhi[o] = hi;
            dlo[o] = f2bf(v - bf2f(hi));
        }
    }
}

// ---------------- Stage 2 (fused): scores + per-wave register top-16 + softmax + gather ----------------
// grid: 8192/8 = 1024 blocks, 512 threads (8 waves). Wave w owns row blockIdx.x*8+w.
// Proven round-12 structure (1 row/wave, sc[32], VGPR~64, no spill) + in-register gather tail.
__global__ __launch_bounds__(512, 4) void attn_fused_kernel(
    const float* __restrict__ Q, const float* __restrict__ K,
    const float* __restrict__ log_temp,
    const float* __restrict__ states, float* __restrict__ incoming)
{
    const int t = threadIdx.x;
    const int w = t >> 6, l = t & 63;
    const int row = blockIdx.x * 8 + w;
    const int b = row >> 11;

    __shared__ float Ksh[128][68];

    const float temp = fminf(fmaxf(expf(log_temp[0]), 0.1f), 10.0f);
    const float scale = 1.0f / (8.0f * temp);   // SCALE = sqrt(64) = 8

    const float* Kb = K + (size_t)b * NN * DP;
    const float4* qr4 = (const float4*)(Q + (size_t)row * DP);

    float sc[32];

    for (int ch = 0; ch < 16; ++ch) {
        __syncthreads();
        {   // stage 128 K rows (each thread 64B contiguous)
            int r = t >> 2, seg = t & 3;
            const float4* src = (const float4*)(Kb + (size_t)(ch * 128 + r) * DP + seg * 16);
            float4* dst = (float4*)&Ksh[r][seg * 16];
            dst[0] = src[0]; dst[1] = src[1]; dst[2] = src[2]; dst[3] = src[3];
        }
        __syncthreads();
        float a0 = 0.f, a1 = 0.f;
        const float4* k0 = (const float4*)&Ksh[l][0];
        const float4* k1 = (const float4*)&Ksh[64 + l][0];
        #pragma unroll
        for (int h = 0; h < 2; ++h) {
            float4 q[8];
            #pragma unroll
            for (int i = 0; i < 8; ++i) q[i] = qr4[h * 8 + i];
            #pragma unroll
            for (int i = 0; i < 8; ++i) {
                float4 kv0 = k0[h * 8 + i];
                float4 kv1 = k1[h * 8 + i];
                a0 = fmaf(kv0.x, q[i].x, fmaf(kv0.y, q[i].y, fmaf(kv0.z, q[i].z, fmaf(kv0.w, q[i].w, a0))));
                a1 = fmaf(kv1.x, q[i].x, fmaf(kv1.y, q[i].y, fmaf(kv1.z, q[i].z, fmaf(kv1.w, q[i].w, a1))));
            }
        }
        sc[ch * 2]     = a0 * scale;
        sc[ch * 2 + 1] = a1 * scale;
    }

    // per-wave top-16 tournament; slot i of lane l holds m = (i>>1)*128 + (i&1)*64 + l
    float wv = 0.f; int wm = 0;
    for (int it = 0; it < KTOP; ++it) {
        float bv = sc[0]; int bs = 0;
        #pragma unroll
        for (int i = 1; i < 32; ++i) {
            bool g = sc[i] > bv;            // strict > keeps earliest slot (smallest m)
            bv = g ? sc[i] : bv;
            bs = g ? i : bs;
        }
        int bm = (bs >> 1) * 128 + (bs & 1) * 64 + l;
        #pragma unroll
        for (int off = 1; off < 64; off <<= 1) {
            float ov = __shfl_xor(bv, off);
            int   om = __shfl_xor(bm, off);
            bool take = (ov > bv) || (ov == bv && om < bm);
            bv = take ? ov : bv;
            bm = take ? om : bm;
        }
        if (l == it) { wv = bv; wm = bm; }
        if ((bm & 63) == l) {
            int s = ((bm >> 7) << 1) | ((bm >> 6) & 1);
            #pragma unroll
            for (int i = 0; i < 32; ++i) if (s == i) sc[i] = -3.0e38f;
        }
    }

    // softmax over the 16 winners (lanes 0..15 hold them, descending)
    float mx = __shfl(wv, 0);
    float e = (l < KTOP) ? expf(wv - mx) : 0.f;
    float Z = e;
    #pragma unroll
    for (int off = 1; off < 64; off <<= 1) Z += __shfl_xor(Z, off);
    float wnorm = e / Z;                    // lane i<16: normalized weight of winner i

    // fused gather: incoming[row] = sum_k w_k * states[b, idx_k]
    const float* Sb = states + (size_t)b * NN * DD;
    f32x4 acc = (f32x4){0.f, 0.f, 0.f, 0.f};
    #pragma unroll
    for (int kk = 0; kk < KTOP; ++kk) {
        float wk = __shfl(wnorm, kk);
        int   ik = __shfl(wm, kk);
        const float4 v = *(const float4*)(Sb + (size_t)ik * DD + l * 4);
        acc[0] = fmaf(wk, v.x, acc[0]);
        acc[1] = fmaf(wk, v.y, acc[1]);
        acc[2] = fmaf(wk, v.z, acc[2]);
        acc[3] = fmaf(wk, v.w, acc[3]);
    }
    *(float4*)(incoming + (size_t)row * DD + l * 4) = *(float4*)&acc;
}

// ---------------- Stage 3 (MFMA): sim -> sigmoid -> normalize -> combined -> mixed ----------------
// incT staging now writes ds_write_b64 (4 bf16 along m) instead of 32 scalar u16 writes/thread.
__global__ __launch_bounds__(256) void coal_kernel(
    const short* __restrict__ pnb_g, const float* __restrict__ incoming,
    const float* __restrict__ temp_coal, float* __restrict__ mixed)
{
    const int b  = blockIdx.x >> 7;
    const int rem = blockIdx.x & 127;
    const int n0 = (rem >> 1) * 32;
    const int dh = rem & 1;
    const int t = threadIdx.x;
    const int w = t >> 6;
    const int l = t & 63;

    __shared__ alignas(16) short pnA[32][72];
    __shared__ alignas(16) short pnB[64][72];
    __shared__ alignas(16) short cwt[32][72];
    __shared__ alignas(16) short incT[128][72];
    __shared__ float rowsum[32];

    const size_t bbase = (size_t)b * NN;

    {
        int r = t >> 3, k8 = (t & 7) * 8;
        *(short8*)&pnA[r][k8] = *(const short8*)(pnb_g + (bbase + n0 + r) * DP + k8);
    }
    if (t < 32) rowsum[t] = 0.0f;

    const float tc = temp_coal[0];

    f32x4 acc[2][2];
    #pragma unroll
    for (int i = 0; i < 2; ++i)
        #pragma unroll
        for (int j = 0; j < 2; ++j)
            acc[i][j] = (f32x4){0.f, 0.f, 0.f, 0.f};

    const int lrow = l & 15;
    const int lk   = (l >> 4) * 8;

    for (int ch = 0; ch < 32; ++ch) {
        const int m0 = ch * 64;
        __syncthreads();

        {
            int r = t >> 2, kq = (t & 3) * 16;
            const short* src = pnb_g + (bbase + m0 + r) * DP + kq;
            *(short8*)&pnB[r][kq]     = *(const short8*)src;
            *(short8*)&pnB[r][kq + 8] = *(const short8*)(src + 8);
        }
        {   // incT staging: each task = 4m x 4d sub-tile; 4 float4 loads + 4 ds_write_b64
            #pragma unroll
            for (int rep = 0; rep < 2; ++rep) {
                int id = t + rep * 256;
                int mq = id & 15;            // m-quad 0..15
                int dq = id >> 4;            // d-quad 0..31
                const float* incb = incoming + (bbase + m0 + mq * 4) * DD + dh * 128 + dq * 4;
                short4v col0, col1, col2, col3;
                #pragma unroll
                for (int mm = 0; mm < 4; ++mm) {
                    float4 v = *(const float4*)(incb + (size_t)mm * DD);
                    col0[mm] = f2bf(v.x);
                    col1[mm] = f2bf(v.y);
                    col2[mm] = f2bf(v.z);
                    col3[mm] = f2bf(v.w);
                }
                *(short4v*)&incT[dq * 4 + 0][mq * 4] = col0;
                *(short4v*)&incT[dq * 4 + 1][mq * 4] = col1;
                *(short4v*)&incT[dq * 4 + 2][mq * 4] = col2;
                *(short4v*)&incT[dq * 4 + 3][mq * 4] = col3;
            }
        }
        __syncthreads();

        f32x4 sacc[2];
        sacc[0] = (f32x4){0.f, 0.f, 0.f, 0.f};
        sacc[1] = (f32x4){0.f, 0.f, 0.f, 0.f};
        #pragma unroll
        for (int ks = 0; ks < 2; ++ks) {
            short8 bfr = *(const short8*)&pnB[w * 16 + lrow][lk + ks * 32];
            short8 a0  = *(const short8*)&pnA[lrow][lk + ks * 32];
            short8 a1  = *(const short8*)&pnA[16 + lrow][lk + ks * 32];
            sacc[0] = __builtin_amdgcn_mfma_f32_16x16x32_bf16(a0, bfr, sacc[0], 0, 0, 0);
            sacc[1] = __builtin_amdgcn_mfma_f32_16x16x32_bf16(a1, bfr, sacc[1], 0, 0, 0);
        }
        #pragma unroll
        for (int rt = 0; rt < 2; ++rt) {
            #pragma unroll
            for (int j = 0; j < 4; ++j) {
                int rr = rt * 16 + (l >> 4) * 4 + j;
                int cc = w * 16 + lrow;
                float cv = 1.0f / (1.0f + expf(-(sacc[rt][j] - 0.7f) * tc));
                cwt[rr][cc] = f2bf(cv);
            }
        }
        __syncthreads();

        {
            int r = t >> 3, c8 = (t & 7) * 8;
            short8 cv = *(const short8*)&cwt[r][c8];
            float p = 0.f;
            #pragma unroll
            for (int j = 0; j < 8; ++j) p += bf2f(cv[j]);
            p += __shfl_xor(p, 1);
            p += __shfl_xor(p, 2);
            p += __shfl_xor(p, 4);
            if ((t & 7) == 0) rowsum[r] += p;
        }

        #pragma unroll
        for (int ks = 0; ks < 2; ++ks) {
            short8 a0 = *(const short8*)&cwt[lrow][lk + ks * 32];
            short8 a1 = *(const short8*)&cwt[16 + lrow][lk + ks * 32];
            #pragma unroll
            for (int ct = 0; ct < 2; ++ct) {
                short8 bfr = *(const short8*)&incT[w * 32 + ct * 16 + lrow][lk + ks * 32];
                acc[0][ct] = __builtin_amdgcn_mfma_f32_16x16x32_bf16(a0, bfr, acc[0][ct], 0, 0, 0);
                acc[1][ct] = __builtin_amdgcn_mfma_f32_16x16x32_bf16(a1, bfr, acc[1][ct], 0, 0, 0);
            }
        }
    }
    __syncthreads();

    #pragma unroll
    for (int rt = 0; rt < 2; ++rt) {
        #pragma unroll
        for (int ct = 0; ct < 2; ++ct) {
            #pragma unroll
            for (int j = 0; j < 4; ++j) {
                int rr = rt * 16 + (l >> 4) * 4 + j;
                int cc = w * 32 + ct * 16 + lrow;
                float inv = 1.0f / (rowsum[rr] + 1e-8f);
                float comb = acc[rt][ct][j] * inv;
                size_t gi = (bbase + n0 + rr) * DD + dh * 128 + cc;
                mixed[gi] = 0.8f * incoming[gi] + 0.2f * comb;
            }
        }
    }
}

// ---------------- Stage 4a (MFMA): z = mixed@W2h + b2h -> q bits only ----------------
__global__ __launch_bounds__(256) void hdcA_kernel(
    const float* __restrict__ mixed,
    const short* __restrict__ W2hT_hi, const short* __restrict__ W2hT_lo,
    const float* __restrict__ b2h,
    unsigned short* __restrict__ qbits)
{
    const int rb = blockIdx.x >> 3;
    const int hs = blockIdx.x & 7;
    const int row0 = rb * 32;
    const int hbase = hs * 256;
    const int t = threadIdx.x;
    const int w = t >> 6, l = t & 63;
    const int lr = l & 15, lg = l >> 4;

    __shared__ short Ahi[32][264], Alo[32][264];
    __shared__ short Whi[64][136], Wlo[64][136];

    #pragma unroll
    for (int i = 0; i < 8; ++i) {
        int idx = t + i * 256;
        int r = idx >> 6, c = (idx & 63) * 4;
        float4 v = *(const float4*)(mixed + (size_t)(row0 + r) * DD + c);
        short4v hi4, lo4;
        hi4[0] = f2bf(v.x); lo4[0] = f2bf(v.x - bf2f(hi4[0]));
        hi4[1] = f2bf(v.y); lo4[1] = f2bf(v.y - bf2f(hi4[1]));
        hi4[2] = f2bf(v.z); lo4[2] = f2bf(v.z - bf2f(hi4[2]));
        hi4[3] = f2bf(v.w); lo4[3] = f2bf(v.w - bf2f(hi4[3]));
        *(short4v*)&Ahi[r][c] = hi4;
        *(short4v*)&Alo[r][c] = lo4;
    }

    for (int ch = 0; ch < 4; ++ch) {
        const int h0 = hbase + ch * 64;
        f32x4 zac[2];
        zac[0] = (f32x4){0.f, 0.f, 0.f, 0.f};
        zac[1] = (f32x4){0.f, 0.f, 0.f, 0.f};
        #pragma unroll
        for (int ks = 0; ks < 2; ++ks) {
            const int k0 = ks * 128;
            __syncthreads();
            {
                int r = t >> 2, cb = (t & 3) * 32;
                const short* sh = W2hT_hi + (size_t)(h0 + r) * DD + k0 + cb;
                const short* sl = W2hT_lo + (size_t)(h0 + r) * DD + k0 + cb;
                #pragma unroll
                for (int j = 0; j < 4; ++j) {
                    *(short8*)&Whi[r][cb + j * 8] = *(const short8*)(sh + j * 8);
                    *(short8*)&Wlo[r][cb + j * 8] = *(const short8*)(sl + j * 8);
                }
            }
            __syncthreads();
            #pragma unroll
            for (int kt = 0; kt < 4; ++kt) {
                int kk = k0 + kt * 32 + lg * 8;
                int kw = kt * 32 + lg * 8;
                short8 bhi = *(const short8*)&Whi[w * 16 + lr][kw];
                short8 blo = *(const short8*)&Wlo[w * 16 + lr][kw];
                #pragma unroll
                for (int mt = 0; mt < 2; ++mt) {
                    short8 ahi = *(const short8*)&Ahi[mt * 16 + lr][kk];
                    short8 alo = *(const short8*)&Alo[mt * 16 + lr][kk];
                    zac[mt] = __builtin_amdgcn_mfma_f32_16x16x32_bf16(ahi, bhi, zac[mt], 0, 0, 0);
                    zac[mt] = __builtin_amdgcn_mfma_f32_16x16x32_bf16(ahi, blo, zac[mt], 0, 0, 0);
                    zac[mt] = __builtin_amdgcn_mfma_f32_16x16x32_bf16(alo, bhi, zac[mt], 0, 0, 0);
                }
            }
        }
        const float bv = b2h[h0 + w * 16 + lr];
        #pragma unroll
        for (int mt = 0; mt < 2; ++mt) {
            #pragma unroll
            for (int j = 0; j < 4; ++j) {
                float z = zac[mt][j] + bv;
                unsigned long long bal = __ballot(z >= 0.0f);
                if (lr == 0)
                    qbits[(size_t)(row0 + mt * 16 + lg * 4 + j) * 128 + (h0 >> 4) + w] =
                        (unsigned short)((bal >> (lg * 16)) & 0xFFFFull);
            }
        }
    }
}

// ---------------- Stage 4b (MFMA): nm recompute + num/ns + strength + recall + out ----------------
__global__ __launch_bounds__(512) void hdcB_kernel(
    const float* __restrict__ mem, const unsigned short* __restrict__ qbits,
    const float* __restrict__ pos_codes, const int* __restrict__ step,
    const short* __restrict__ WfhT_hi,
    const float* __restrict__ bfh, const float* __restrict__ keys,
    const float* __restrict__ mixed, float* __restrict__ out)
{
    const int mb = blockIdx.x >> 1, nb = blockIdx.x & 1;
    const int row0 = mb * 32, d0 = nb * 128;
    const int t = threadIdx.x;
    const int w = t >> 6, l = t & 63;
    const int wm = w >> 2, wn = w & 3;
    const int lr = l & 15, lg = l >> 4;

    __shared__ short Ahi[32][72], Alo[32][72];
    __shared__ short Bhi[128][72];
    __shared__ float sred[32][2];
    __shared__ float strenL[32];

    int st = ((step[0] % 256) + 256) % 256;
    const float* pos = pos_codes + (size_t)st * HH;

    f32x4 acc[2];
    acc[0] = (f32x4){0.f, 0.f, 0.f, 0.f};
    acc[1] = (f32x4){0.f, 0.f, 0.f, 0.f};
    float pnum = 0.f, pns = 0.f;

    const int ar = t >> 4;              // row 0..31
    const int ah = (t & 15) * 4;        // h offset within 64-chunk
    const int arow = row0 + ar;
    const size_t memb = (size_t)arow * HH;
    const size_t keyb = (size_t)(arow & (NN - 1)) * HH;

    for (int kc = 0; kc < 32; ++kc) {
        const int h0 = kc * 64;
        __syncthreads();
        {   // A stage: nm recompute + num/ns partials (coalesced float4 loads)
            float4 mv = *(const float4*)(mem + memb + h0 + ah);
            float4 kv = *(const float4*)(keys + keyb + h0 + ah);
            float4 pv = *(const float4*)(pos + h0 + ah);
            unsigned bits = (unsigned)qbits[(size_t)arow * 128 + ((h0 + ah) >> 4)] >> (ah & 15);
            float mvs[4] = { mv.x, mv.y, mv.z, mv.w };
            float kvs[4] = { kv.x, kv.y, kv.z, kv.w };
            float pvs[4] = { pv.x, pv.y, pv.z, pv.w };
            short4v hi4, lo4;
            #pragma unroll
            for (int j = 0; j < 4; ++j) {
                float q = ((bits >> j) & 1u) ? 1.0f : -1.0f;
                float nmv = fmaf(0.05f * q, pvs[j], 0.95f * mvs[j]);
                pnum = fmaf(nmv, q * kvs[j], pnum);
                pns  = fmaf(nmv, nmv, pns);
                hi4[j] = f2bf(nmv);
                lo4[j] = f2bf(nmv - bf2f(hi4[j]));
            }
            *(short4v*)&Ahi[ar][ah] = hi4;
            *(short4v*)&Alo[ar][ah] = lo4;
        }
        {   // B stage: WfhT 128 x 64 (hi only)
            int r = t >> 2, hb = (t & 3) * 16;
            const short* sh = WfhT_hi + (size_t)(d0 + r) * HH + h0 + hb;
            *(short8*)&Bhi[r][hb]     = *(const short8*)sh;
            *(short8*)&Bhi[r][hb + 8] = *(const short8*)(sh + 8);
        }
        __syncthreads();
        #pragma unroll
        for (int kt = 0; kt < 2; ++kt) {
            const int kk = kt * 32 + lg * 8;
            short8 ahi = *(const short8*)&Ahi[wm * 16 + lr][kk];
            short8 alo = *(const short8*)&Alo[wm * 16 + lr][kk];
            #pragma unroll
            for (int nt = 0; nt < 2; ++nt) {
                short8 bhi = *(const short8*)&Bhi[wn * 32 + nt * 16 + lr][kk];
                acc[nt] = __builtin_amdgcn_mfma_f32_16x16x32_bf16(ahi, bhi, acc[nt], 0, 0, 0);
                acc[nt] = __builtin_amdgcn_mfma_f32_16x16x32_bf16(alo, bhi, acc[nt], 0, 0, 0);
            }
        }
    }

    // num/ns: reduce across the 16 threads sharing each row (same wave)
    #pragma unroll
    for (int off = 1; off < 16; off <<= 1) {
        pnum += __shfl_xor(pnum, off);
        pns  += __shfl_xor(pns, off);
    }
    if ((t & 15) == 0) { sred[ar][0] = pnum; sred[ar][1] = pns; }
    __syncthreads();
    if (t < 32) {
        float cosv = sred[t][0] / (fmaxf(sqrtf(sred[t][1]), 1e-8f) * sqrtf(2048.0f));
        strenL[t] = 1.0f / (1.0f + expf(-cosv));
    }
    __syncthreads();

    #pragma unroll
    for (int nt = 0; nt < 2; ++nt) {
        #pragma unroll
        for (int j = 0; j < 4; ++j) {
            int rloc = wm * 16 + lg * 4 + j;
            int col = d0 + wn * 32 + nt * 16 + lr;
            size_t gi = (size_t)(row0 + rloc) * DD + col;
            out[gi] = mixed[gi] + (acc[nt][j] + bfh[col]) * strenL[rloc];
        }
    }
}

extern "C" void kernel_launch(void* const* d_in, const int* in_sizes, int n_in,
                              void* d_out, int out_size, void* d_ws, size_t ws_size,
                              hipStream_t stream) {
    const float* states    = (const float*)d_in[0];
    const float* actions   = (const float*)d_in[1];
    const float* mem       = (const float*)d_in[2];
    const float* Wq        = (const float*)d_in[3];
    const float* bq        = (const float*)d_in[4];
    const float* Wk        = (const float*)d_in[5];
    const float* bk        = (const float*)d_in[6];
    const float* log_temp  = (const float*)d_in[7];
    const float* Wc        = (const float*)d_in[8];
    const float* bc        = (const float*)d_in[9];
    const float* temp_coal = (const float*)d_in[10];
    const float* W2h       = (const float*)d_in[11];
    const float* b2h       = (const float*)d_in[12];
    const float* Wfh       = (const float*)d_in[13];
    const float* bfh       = (const float*)d_in[14];
    const float* keys      = (const float*)d_in[15];
    const float* pos_codes = (const float*)d_in[16];
    const int*   step      = (const int*)d_in[17];
    float* out = (float*)d_out;

    float* ws = (float*)d_ws;
    float* mixed    = ws;                                    // 2,097,152 f32
    short* W2hT_hi  = (short*)(mixed + 2097152);             // 524288 shorts
    short* W2hT_lo  = W2hT_hi + 524288;
    short* WfhT_hi  = W2hT_lo + 524288;
    short* WfhT_lo  = WfhT_hi + 524288;
    unsigned short* qbits = (unsigned short*)(WfhT_lo + 524288);  // 1,048,576 u16
    float* Q        = (float*)(qbits + 1048576);             // 524288 f32
    float* K        = Q + 524288;
    float* incoming = K + 524288;                            // 2,097,152 f32
    short* pn_bf    = (short*)(incoming + 2097152);          // 524288 shorts

    head_kernel<<<1536, 256, 0, stream>>>(actions, Wq, bq, Wk, bk, Wc, bc, W2h, Wfh,
                                          Q, K, pn_bf, W2hT_hi, W2hT_lo, WfhT_hi, WfhT_lo);
    attn_fused_kernel<<<BATCH * NN / 8, 512, 0, stream>>>(Q, K, log_temp, states, incoming);
    coal_kernel<<<BATCH * (NN / 32) * 2, 256, 0, stream>>>(pn_bf, incoming, temp_coal, mixed);
    hdcA_kernel<<<(BATCH * NN / 32) * 8, 256, 0, stream>>>(mixed, W2hT_hi, W2hT_lo, b2h, qbits);
    hdcB_kernel<<<(BATCH * NN / 32) * 2, 512, 0, stream>>>(mem, qbits, pos_codes, step,
                                                           WfhT_hi, bfh, keys, mixed, out);
}

// Round 18
// 327.003 us; speedup vs baseline: 1.0893x; 1.0153x over previous
//
#include <hip/hip_runtime.h>
#include <math.h>

#define BATCH 4
#define NN 2048
#define DD 256
#define HH 2048
#define DP 64
#define KTOP 16

typedef float f32x4 __attribute__((ext_vector_type(4)));
typedef short short8 __attribute__((ext_vector_type(8)));
typedef short short4v __attribute__((ext_vector_type(4)));

__device__ __forceinline__ short f2bf(float x) {
    union { float f; unsigned u; } v; v.f = x;
    unsigned r = v.u + 0x7FFFu + ((v.u >> 16) & 1u);   // round-to-nearest-even
    return (short)(r >> 16);
}
__device__ __forceinline__ float bf2f(short s) {
    union { unsigned u; float f; } v; v.u = ((unsigned)(unsigned short)s) << 16;
    return v.f;
}

// ---------------- Head: fused proj (blocks 0..511) + weight prep (blocks 512..1535, hi only) -------
__global__ __launch_bounds__(256) void head_kernel(
    const float* __restrict__ act,
    const float* __restrict__ Wq, const float* __restrict__ bq,
    const float* __restrict__ Wk, const float* __restrict__ bk,
    const float* __restrict__ Wc, const float* __restrict__ bc,
    const float* __restrict__ W2h, const float* __restrict__ Wfh,
    float* __restrict__ Qo, float* __restrict__ Ko, short* __restrict__ Pno,
    short* __restrict__ W2hT_hi, short* __restrict__ WfhT_hi)
{
    __shared__ float smem[16 * 256];   // 16 KB, aliased by both parts

    if (blockIdx.x < 512) {
        // ---- proj: rows row0 .. row0+15 ----
        float (*rowbuf)[256] = (float(*)[256])smem;
        const int row0 = blockIdx.x * 16;
        const int t = threadIdx.x;
        const int wave = t >> 6, lane = t & 63;
        const float* src = act + (size_t)row0 * DD;
        for (int i = t; i < 16 * DD; i += 256) rowbuf[i >> 8][i & 255] = src[i];
        __syncthreads();

        float q[4], k[4], c[4];
        #pragma unroll
        for (int r = 0; r < 4; ++r) { q[r] = bq[lane]; k[r] = bk[lane]; c[r] = bc[lane]; }

        for (int d = 0; d < DD; ++d) {
            float wq = Wq[d * DP + lane];
            float wk = Wk[d * DP + lane];
            float wc = Wc[d * DP + lane];
            #pragma unroll
            for (int r = 0; r < 4; ++r) {
                float av = rowbuf[wave * 4 + r][d];
                q[r] = fmaf(av, wq, q[r]);
                k[r] = fmaf(av, wk, k[r]);
                c[r] = fmaf(av, wc, c[r]);
            }
        }
        #pragma unroll
        for (int r = 0; r < 4; ++r) {
            float ss = c[r] * c[r];
            #pragma unroll
            for (int off = 32; off; off >>= 1) ss += __shfl_xor(ss, off);
            float nrm = fmaxf(sqrtf(ss), 1e-12f);
            size_t o = (size_t)(row0 + wave * 4 + r) * DP + lane;
            Qo[o] = q[r];
            Ko[o] = k[r];
            Pno[o] = f2bf(c[r] / nrm);
        }
    } else {
        // ---- prep: transpose + bf16 hi (lo arrays are no longer consumed anywhere) ----
        float (*tile)[33] = (float(*)[33])smem;
        int b = blockIdx.x - 512;
        const float* src; short* dhi; int R, C, r0, c0;
        if (b < 512) {               // W2h [256][2048] -> W2hT [2048][256]
            src = W2h; dhi = W2hT_hi; R = 256; C = 2048;
            r0 = (b >> 6) * 32; c0 = (b & 63) * 32;
        } else {                     // Wfh [2048][256] -> WfhT [256][2048]
            b -= 512;
            src = Wfh; dhi = WfhT_hi; R = 2048; C = 256;
            r0 = (b >> 3) * 32; c0 = (b & 7) * 32;
        }
        int tx = threadIdx.x & 31, ty = threadIdx.x >> 5;
        #pragma unroll
        for (int i = 0; i < 4; ++i)
            tile[ty + 8 * i][tx] = src[(size_t)(r0 + ty + 8 * i) * C + c0 + tx];
        __syncthreads();
        #pragma unroll
        for (int i = 0; i < 4; ++i) {
            float v = tile[tx][ty + 8 * i];
            size_t o = (size_t)(c0 + ty + 8 * i) * R + r0 + tx;
            dhi[o] = f2bf(v);
        }
    }
}

// ---------------- Stage 2 (fused): scores + per-wave register top-16 + softmax + gather ----------------
// grid: 8192/8 = 1024 blocks, 512 threads (8 waves). Wave w owns row blockIdx.x*8+w.
// Proven round-12 structure (1 row/wave, sc[32], VGPR~64, no spill) + in-register gather tail.
__global__ __launch_bounds__(512, 4) void attn_fused_kernel(
    const float* __restrict__ Q, const float* __restrict__ K,
    const float* __restrict__ log_temp,
    const float* __restrict__ states, float* __restrict__ incoming)
{
    const int t = threadIdx.x;
    const int w = t >> 6, l = t & 63;
    const int row = blockIdx.x * 8 + w;
    const int b = row >> 11;

    __shared__ float Ksh[128][68];

    const float temp = fminf(fmaxf(expf(log_temp[0]), 0.1f), 10.0f);
    const float scale = 1.0f / (8.0f * temp);   // SCALE = sqrt(64) = 8

    const float* Kb = K + (size_t)b * NN * DP;
    const float4* qr4 = (const float4*)(Q + (size_t)row * DP);

    float sc[32];

    for (int ch = 0; ch < 16; ++ch) {
        __syncthreads();
        {   // stage 128 K rows (each thread 64B contiguous)
            int r = t >> 2, seg = t & 3;
            const float4* src = (const float4*)(Kb + (size_t)(ch * 128 + r) * DP + seg * 16);
            float4* dst = (float4*)&Ksh[r][seg * 16];
            dst[0] = src[0]; dst[1] = src[1]; dst[2] = src[2]; dst[3] = src[3];
        }
        __syncthreads();
        float a0 = 0.f, a1 = 0.f;
        const float4* k0 = (const float4*)&Ksh[l][0];
        const float4* k1 = (const float4*)&Ksh[64 + l][0];
        #pragma unroll
        for (int h = 0; h < 2; ++h) {
            float4 q[8];
            #pragma unroll
            for (int i = 0; i < 8; ++i) q[i] = qr4[h * 8 + i];
            #pragma unroll
            for (int i = 0; i < 8; ++i) {
                float4 kv0 = k0[h * 8 + i];
                float4 kv1 = k1[h * 8 + i];
                a0 = fmaf(kv0.x, q[i].x, fmaf(kv0.y, q[i].y, fmaf(kv0.z, q[i].z, fmaf(kv0.w, q[i].w, a0))));
                a1 = fmaf(kv1.x, q[i].x, fmaf(kv1.y, q[i].y, fmaf(kv1.z, q[i].z, fmaf(kv1.w, q[i].w, a1))));
            }
        }
        sc[ch * 2]     = a0 * scale;
        sc[ch * 2 + 1] = a1 * scale;
    }

    // per-wave top-16 tournament; slot i of lane l holds m = (i>>1)*128 + (i&1)*64 + l
    float wv = 0.f; int wm = 0;
    for (int it = 0; it < KTOP; ++it) {
        float bv = sc[0]; int bs = 0;
        #pragma unroll
        for (int i = 1; i < 32; ++i) {
            bool g = sc[i] > bv;            // strict > keeps earliest slot (smallest m)
            bv = g ? sc[i] : bv;
            bs = g ? i : bs;
        }
        int bm = (bs >> 1) * 128 + (bs & 1) * 64 + l;
        #pragma unroll
        for (int off = 1; off < 64; off <<= 1) {
            float ov = __shfl_xor(bv, off);
            int   om = __shfl_xor(bm, off);
            bool take = (ov > bv) || (ov == bv && om < bm);
            bv = take ? ov : bv;
            bm = take ? om : bm;
        }
        if (l == it) { wv = bv; wm = bm; }
        if ((bm & 63) == l) {
            int s = ((bm >> 7) << 1) | ((bm >> 6) & 1);
            #pragma unroll
            for (int i = 0; i < 32; ++i) if (s == i) sc[i] = -3.0e38f;
        }
    }

    // softmax over the 16 winners (lanes 0..15 hold them, descending)
    float mx = __shfl(wv, 0);
    float e = (l < KTOP) ? expf(wv - mx) : 0.f;
    float Z = e;
    #pragma unroll
    for (int off = 1; off < 64; off <<= 1) Z += __shfl_xor(Z, off);
    float wnorm = e / Z;                    // lane i<16: normalized weight of winner i

    // fused gather: incoming[row] = sum_k w_k * states[b, idx_k]
    const float* Sb = states + (size_t)b * NN * DD;
    f32x4 acc = (f32x4){0.f, 0.f, 0.f, 0.f};
    #pragma unroll
    for (int kk = 0; kk < KTOP; ++kk) {
        float wk = __shfl(wnorm, kk);
        int   ik = __shfl(wm, kk);
        const float4 v = *(const float4*)(Sb + (size_t)ik * DD + l * 4);
        acc[0] = fmaf(wk, v.x, acc[0]);
        acc[1] = fmaf(wk, v.y, acc[1]);
        acc[2] = fmaf(wk, v.z, acc[2]);
        acc[3] = fmaf(wk, v.w, acc[3]);
    }
    *(float4*)(incoming + (size_t)row * DD + l * 4) = *(float4*)&acc;
}

// ---------------- Stage 3 (MFMA, merged d-halves): sim once -> sigmoid -> combined -> mixed -------
// grid: BATCH*(NN/32) = 256 blocks, 512 threads (8 waves). Block: 32 rows x all 256 d-cols.
// sim/sigmoid/rowsum computed ONCE (was duplicated per d-half); gemm2 identical per-wave code,
// 8 waves cover 256 cols. Bit-identical output to the 2-block version.
__global__ __launch_bounds__(512) void coal_kernel(
    const short* __restrict__ pnb_g, const float* __restrict__ incoming,
    const float* __restrict__ temp_coal, float* __restrict__ mixed)
{
    const int b  = blockIdx.x >> 6;
    const int n0 = (blockIdx.x & 63) * 32;
    const int t = threadIdx.x;
    const int w = t >> 6;
    const int l = t & 63;

    __shared__ alignas(16) short pnA[32][72];
    __shared__ alignas(16) short pnB[64][72];
    __shared__ alignas(16) short cwt[32][72];
    __shared__ alignas(16) short incT[256][72];   // 36 KB: d-major, full 256 cols
    __shared__ float rowsum[32];

    const size_t bbase = (size_t)b * NN;

    if (t < 256) {
        int r = t >> 3, k8 = (t & 7) * 8;
        *(short8*)&pnA[r][k8] = *(const short8*)(pnb_g + (bbase + n0 + r) * DP + k8);
    }
    if (t < 32) rowsum[t] = 0.0f;

    const float tc = temp_coal[0];

    f32x4 acc[2][2];
    #pragma unroll
    for (int i = 0; i < 2; ++i)
        #pragma unroll
        for (int j = 0; j < 2; ++j)
            acc[i][j] = (f32x4){0.f, 0.f, 0.f, 0.f};

    const int lrow = l & 15;
    const int lk   = (l >> 4) * 8;

    for (int ch = 0; ch < 32; ++ch) {
        const int m0 = ch * 64;
        __syncthreads();

        {   // pnB: 64 x 64 shorts, 512 threads x 1 short8
            int r = t >> 3, k8 = (t & 7) * 8;
            *(short8*)&pnB[r][k8] = *(const short8*)(pnb_g + (bbase + m0 + r) * DP + k8);
        }
        {   // incT staging: 4m x 4d sub-tiles; 1024 tasks over 512 threads x 2 reps
            #pragma unroll
            for (int rep = 0; rep < 2; ++rep) {
                int id = t + rep * 512;
                int mq = id & 15;            // m-quad 0..15
                int dq = id >> 4;            // d-quad 0..63
                const float* incb = incoming + (bbase + m0 + mq * 4) * DD + dq * 4;
                short4v col0, col1, col2, col3;
                #pragma unroll
                for (int mm = 0; mm < 4; ++mm) {
                    float4 v = *(const float4*)(incb + (size_t)mm * DD);
                    col0[mm] = f2bf(v.x);
                    col1[mm] = f2bf(v.y);
                    col2[mm] = f2bf(v.z);
                    col3[mm] = f2bf(v.w);
                }
                *(short4v*)&incT[dq * 4 + 0][mq * 4] = col0;
                *(short4v*)&incT[dq * 4 + 1][mq * 4] = col1;
                *(short4v*)&incT[dq * 4 + 2][mq * 4] = col2;
                *(short4v*)&incT[dq * 4 + 3][mq * 4] = col3;
            }
        }
        __syncthreads();

        if (w < 4) {   // sim: waves 0..3 compute cwt cols w*16..w*16+15 (once, not per d-half)
            f32x4 sacc[2];
            sacc[0] = (f32x4){0.f, 0.f, 0.f, 0.f};
            sacc[1] = (f32x4){0.f, 0.f, 0.f, 0.f};
            #pragma unroll
            for (int ks = 0; ks < 2; ++ks) {
                short8 bfr = *(const short8*)&pnB[w * 16 + lrow][lk + ks * 32];
                short8 a0  = *(const short8*)&pnA[lrow][lk + ks * 32];
                short8 a1  = *(const short8*)&pnA[16 + lrow][lk + ks * 32];
                sacc[0] = __builtin_amdgcn_mfma_f32_16x16x32_bf16(a0, bfr, sacc[0], 0, 0, 0);
                sacc[1] = __builtin_amdgcn_mfma_f32_16x16x32_bf16(a1, bfr, sacc[1], 0, 0, 0);
            }
            #pragma unroll
            for (int rt = 0; rt < 2; ++rt) {
                #pragma unroll
                for (int j = 0; j < 4; ++j) {
                    int rr = rt * 16 + (l >> 4) * 4 + j;
                    int cc = w * 16 + lrow;
                    float cv = 1.0f / (1.0f + expf(-(sacc[rt][j] - 0.7f) * tc));
                    cwt[rr][cc] = f2bf(cv);
                }
            }
        }
        __syncthreads();

        if (t < 256) {   // rowsum partial (once)
            int r = t >> 3, c8 = (t & 7) * 8;
            short8 cv = *(const short8*)&cwt[r][c8];
            float p = 0.f;
            #pragma unroll
            for (int j = 0; j < 8; ++j) p += bf2f(cv[j]);
            p += __shfl_xor(p, 1);
            p += __shfl_xor(p, 2);
            p += __shfl_xor(p, 4);
            if ((t & 7) == 0) rowsum[r] += p;
        }

        // gemm2: 8 waves cover cols 0..255 (wave w -> w*32..w*32+31)
        #pragma unroll
        for (int ks = 0; ks < 2; ++ks) {
            short8 a0 = *(const short8*)&cwt[lrow][lk + ks * 32];
            short8 a1 = *(const short8*)&cwt[16 + lrow][lk + ks * 32];
            #pragma unroll
            for (int ct = 0; ct < 2; ++ct) {
                short8 bfr = *(const short8*)&incT[w * 32 + ct * 16 + lrow][lk + ks * 32];
                acc[0][ct] = __builtin_amdgcn_mfma_f32_16x16x32_bf16(a0, bfr, acc[0][ct], 0, 0, 0);
                acc[1][ct] = __builtin_amdgcn_mfma_f32_16x16x32_bf16(a1, bfr, acc[1][ct], 0, 0, 0);
            }
        }
    }
    __syncthreads();

    #pragma unroll
    for (int rt = 0; rt < 2; ++rt) {
        #pragma unroll
        for (int ct = 0; ct < 2; ++ct) {
            #pragma unroll
            for (int j = 0; j < 4; ++j) {
                int rr = rt * 16 + (l >> 4) * 4 + j;
                int cc = w * 32 + ct * 16 + lrow;
                float inv = 1.0f / (rowsum[rr] + 1e-8f);
                float comb = acc[rt][ct][j] * inv;
                size_t gi = (bbase + n0 + rr) * DD + cc;
                mixed[gi] = 0.8f * incoming[gi] + 0.2f * comb;
            }
        }
    }
}

// ---------------- Stage 4a (MFMA): z = mixed@W2h + b2h -> q bits; 2-term split (a_hi+a_lo)*b_hi ---
__global__ __launch_bounds__(256) void hdcA_kernel(
    const float* __restrict__ mixed,
    const short* __restrict__ W2hT_hi,
    const float* __restrict__ b2h,
    unsigned short* __restrict__ qbits)
{
    const int rb = blockIdx.x >> 3;
    const int hs = blockIdx.x & 7;
    const int row0 = rb * 32;
    const int hbase = hs * 256;
    const int t = threadIdx.x;
    const int w = t >> 6, l = t & 63;
    const int lr = l & 15, lg = l >> 4;

    __shared__ short Ahi[32][264], Alo[32][264];
    __shared__ short Whi[64][136];

    #pragma unroll
    for (int i = 0; i < 8; ++i) {
        int idx = t + i * 256;
        int r = idx >> 6, c = (idx & 63) * 4;
        float4 v = *(const float4*)(mixed + (size_t)(row0 + r) * DD + c);
        short4v hi4, lo4;
        hi4[0] = f2bf(v.x); lo4[0] = f2bf(v.x - bf2f(hi4[0]));
        hi4[1] = f2bf(v.y); lo4[1] = f2bf(v.y - bf2f(hi4[1]));
        hi4[2] = f2bf(v.z); lo4[2] = f2bf(v.z - bf2f(hi4[2]));
        hi4[3] = f2bf(v.w); lo4[3] = f2bf(v.w - bf2f(hi4[3]));
        *(short4v*)&Ahi[r][c] = hi4;
        *(short4v*)&Alo[r][c] = lo4;
    }

    for (int ch = 0; ch < 4; ++ch) {
        const int h0 = hbase + ch * 64;
        f32x4 zac[2];
        zac[0] = (f32x4){0.f, 0.f, 0.f, 0.f};
        zac[1] = (f32x4){0.f, 0.f, 0.f, 0.f};
        #pragma unroll
        for (int ks = 0; ks < 2; ++ks) {
            const int k0 = ks * 128;
            __syncthreads();
            {
                int r = t >> 2, cb = (t & 3) * 32;
                const short* sh = W2hT_hi + (size_t)(h0 + r) * DD + k0 + cb;
                #pragma unroll
                for (int j = 0; j < 4; ++j)
                    *(short8*)&Whi[r][cb + j * 8] = *(const short8*)(sh + j * 8);
            }
            __syncthreads();
            #pragma unroll
            for (int kt = 0; kt < 4; ++kt) {
                int kk = k0 + kt * 32 + lg * 8;
                int kw = kt * 32 + lg * 8;
                short8 bhi = *(const short8*)&Whi[w * 16 + lr][kw];
                #pragma unroll
                for (int mt = 0; mt < 2; ++mt) {
                    short8 ahi = *(const short8*)&Ahi[mt * 16 + lr][kk];
                    short8 alo = *(const short8*)&Alo[mt * 16 + lr][kk];
                    zac[mt] = __builtin_amdgcn_mfma_f32_16x16x32_bf16(ahi, bhi, zac[mt], 0, 0, 0);
                    zac[mt] = __builtin_amdgcn_mfma_f32_16x16x32_bf16(alo, bhi, zac[mt], 0, 0, 0);
                }
            }
        }
        const float bv = b2h[h0 + w * 16 + lr];
        #pragma unroll
        for (int mt = 0; mt < 2; ++mt) {
            #pragma unroll
            for (int j = 0; j < 4; ++j) {
                float z = zac[mt][j] + bv;
                unsigned long long bal = __ballot(z >= 0.0f);
                if (lr == 0)
                    qbits[(size_t)(row0 + mt * 16 + lg * 4 + j) * 128 + (h0 >> 4) + w] =
                        (unsigned short)((bal >> (lg * 16)) & 0xFFFFull);
            }
        }
    }
}

// ---------------- Stage 4b (MFMA): nm recompute + num/ns + strength + recall + out ----------------
__global__ __launch_bounds__(512) void hdcB_kernel(
    const float* __restrict__ mem, const unsigned short* __restrict__ qbits,
    const float* __restrict__ pos_codes, const int* __restrict__ step,
    const short* __restrict__ WfhT_hi,
    const float* __restrict__ bfh, const float* __restrict__ keys,
    const float* __restrict__ mixed, float* __restrict__ out)
{
    const int mb = blockIdx.x >> 1, nb = blockIdx.x & 1;
    const int row0 = mb * 32, d0 = nb * 128;
    const int t = threadIdx.x;
    const int w = t >> 6, l = t & 63;
    const int wm = w >> 2, wn = w & 3;
    const int lr = l & 15, lg = l >> 4;

    __shared__ short Ahi[32][72], Alo[32][72];
    __shared__ short Bhi[128][72];
    __shared__ float sred[32][2];
    __shared__ float strenL[32];

    int st = ((step[0] % 256) + 256) % 256;
    const float* pos = pos_codes + (size_t)st * HH;

    f32x4 acc[2];
    acc[0] = (f32x4){0.f, 0.f, 0.f, 0.f};
    acc[1] = (f32x4){0.f, 0.f, 0.f, 0.f};
    float pnum = 0.f, pns = 0.f;

    const int ar = t >> 4;              // row 0..31
    const int ah = (t & 15) * 4;        // h offset within 64-chunk
    const int arow = row0 + ar;
    const size_t memb = (size_t)arow * HH;
    const size_t keyb = (size_t)(arow & (NN - 1)) * HH;

    for (int kc = 0; kc < 32; ++kc) {
        const int h0 = kc * 64;
        __syncthreads();
        {   // A stage: nm recompute + num/ns partials (coalesced float4 loads)
            float4 mv = *(const float4*)(mem + memb + h0 + ah);
            float4 kv = *(const float4*)(keys + keyb + h0 + ah);
            float4 pv = *(const float4*)(pos + h0 + ah);
            unsigned bits = (unsigned)qbits[(size_t)arow * 128 + ((h0 + ah) >> 4)] >> (ah & 15);
            float mvs[4] = { mv.x, mv.y, mv.z, mv.w };
            float kvs[4] = { kv.x, kv.y, kv.z, kv.w };
            float pvs[4] = { pv.x, pv.y, pv.z, pv.w };
            short4v hi4, lo4;
            #pragma unroll
            for (int j = 0; j < 4; ++j) {
                float q = ((bits >> j) & 1u) ? 1.0f : -1.0f;
                float nmv = fmaf(0.05f * q, pvs[j], 0.95f * mvs[j]);
                pnum = fmaf(nmv, q * kvs[j], pnum);
                pns  = fmaf(nmv, nmv, pns);
                hi4[j] = f2bf(nmv);
                lo4[j] = f2bf(nmv - bf2f(hi4[j]));
            }
            *(short4v*)&Ahi[ar][ah] = hi4;
            *(short4v*)&Alo[ar][ah] = lo4;
        }
        {   // B stage: WfhT 128 x 64 (hi only)
            int r = t >> 2, hb = (t & 3) * 16;
            const short* sh = WfhT_hi + (size_t)(d0 + r) * HH + h0 + hb;
            *(short8*)&Bhi[r][hb]     = *(const short8*)sh;
            *(short8*)&Bhi[r][hb + 8] = *(const short8*)(sh + 8);
        }
        __syncthreads();
        #pragma unroll
        for (int kt = 0; kt < 2; ++kt) {
            const int kk = kt * 32 + lg * 8;
            short8 ahi = *(const short8*)&Ahi[wm * 16 + lr][kk];
            short8 alo = *(const short8*)&Alo[wm * 16 + lr][kk];
            #pragma unroll
            for (int nt = 0; nt < 2; ++nt) {
                short8 bhi = *(const short8*)&Bhi[wn * 32 + nt * 16 + lr][kk];
                acc[nt] = __builtin_amdgcn_mfma_f32_16x16x32_bf16(ahi, bhi, acc[nt], 0, 0, 0);
                acc[nt] = __builtin_amdgcn_mfma_f32_16x16x32_bf16(alo, bhi, acc[nt], 0, 0, 0);
            }
        }
    }

    // num/ns: reduce across the 16 threads sharing each row (same wave)
    #pragma unroll
    for (int off = 1; off < 16; off <<= 1) {
        pnum += __shfl_xor(pnum, off);
        pns  += __shfl_xor(pns, off);
    }
    if ((t & 15) == 0) { sred[ar][0] = pnum; sred[ar][1] = pns; }
    __syncthreads();
    if (t < 32) {
        float cosv = sred[t][0] / (fmaxf(sqrtf(sred[t][1]), 1e-8f) * sqrtf(2048.0f));
        strenL[t] = 1.0f / (1.0f + expf(-cosv));
    }
    __syncthreads();

    #pragma unroll
    for (int nt = 0; nt < 2; ++nt) {
        #pragma unroll
        for (int j = 0; j < 4; ++j) {
            int rloc = wm * 16 + lg * 4 + j;
            int col = d0 + wn * 32 + nt * 16 + lr;
            size_t gi = (size_t)(row0 + rloc) * DD + col;
            out[gi] = mixed[gi] + (acc[nt][j] + bfh[col]) * strenL[rloc];
        }
    }
}

extern "C" void kernel_launch(void* const* d_in, const int* in_sizes, int n_in,
                              void* d_out, int out_size, void* d_ws, size_t ws_size,
                              hipStream_t stream) {
    const float* states    = (const float*)d_in[0];
    const float* actions   = (const float*)d_in[1];
    const float* mem       = (const float*)d_in[2];
    const float* Wq        = (const float*)d_in[3];
    const float* bq        = (const float*)d_in[4];
    const float* Wk        = (const float*)d_in[5];
    const float* bk        = (const float*)d_in[6];
    const float* log_temp  = (const float*)d_in[7];
    const float* Wc        = (const float*)d_in[8];
    const float* bc        = (const float*)d_in[9];
    const float* temp_coal = (const float*)d_in[10];
    const float* W2h       = (const float*)d_in[11];
    const float* b2h       = (const float*)d_in[12];
    const float* Wfh       = (const float*)d_in[13];
    const float* bfh       = (const float*)d_in[14];
    const float* keys      = (const float*)d_in[15];
    const float* pos_codes = (const float*)d_in[16];
    const int*   step      = (const int*)d_in[17];
    float* out = (float*)d_out;

    float* ws = (float*)d_ws;
    float* mixed    = ws;                                    // 2,097,152 f32
    short* W2hT_hi  = (short*)(mixed + 2097152);             // 524288 shorts
    short* WfhT_hi  = W2hT_hi + 524288;
    unsigned short* qbits = (unsigned short*)(WfhT_hi + 524288);  // 1,048,576 u16
    float* Q        = (float*)(qbits + 1048576);             // 524288 f32
    float* K        = Q + 524288;
    float* incoming = K + 524288;                            // 2,097,152 f32
    short* pn_bf    = (short*)(incoming + 2097152);          // 524288 shorts

    head_kernel<<<1536, 256, 0, stream>>>(actions, Wq, bq, Wk, bk, Wc, bc, W2h, Wfh,
                                          Q, K, pn_bf, W2hT_hi, WfhT_hi);
    attn_fused_kernel<<<BATCH * NN / 8, 512, 0, stream>>>(Q, K, log_temp, states, incoming);
    coal_kernel<<<BATCH * (NN / 32), 512, 0, stream>>>(pn_bf, incoming, temp_coal, mixed);
    hdcA_kernel<<<(BATCH * NN / 32) * 8, 256, 0, stream>>>(mixed, W2hT_hi, b2h, qbits);
    hdcB_kernel<<<(BATCH * NN / 32) * 2, 512, 0, stream>>>(mem, qbits, pos_codes, step,
                                                           WfhT_hi, bfh, keys, mixed, out);
}

// Round 19
// 311.024 us; speedup vs baseline: 1.1453x; 1.0514x over previous
//
#include <hip/hip_runtime.h>
#include <math.h>

#define BATCH 4
#define NN 2048
#define DD 256
#define HH 2048
#define DP 64
#define KTOP 16

typedef float f32x4 __attribute__((ext_vector_type(4)));
typedef short short8 __attribute__((ext_vector_type(8)));
typedef short short4v __attribute__((ext_vector_type(4)));

__device__ __forceinline__ short f2bf(float x) {
    union { float f; unsigned u; } v; v.f = x;
    unsigned r = v.u + 0x7FFFu + ((v.u >> 16) & 1u);   // round-to-nearest-even
    return (short)(r >> 16);
}
__device__ __forceinline__ float bf2f(short s) {
    union { unsigned u; float f; } v; v.u = ((unsigned)(unsigned short)s) << 16;
    return v.f;
}

// ---------------- Head: fused proj (blocks 0..511) + weight prep (blocks 512..1535, hi only) -------
__global__ __launch_bounds__(256) void head_kernel(
    const float* __restrict__ act,
    const float* __restrict__ Wq, const float* __restrict__ bq,
    const float* __restrict__ Wk, const float* __restrict__ bk,
    const float* __restrict__ Wc, const float* __restrict__ bc,
    const float* __restrict__ W2h, const float* __restrict__ Wfh,
    float* __restrict__ Qo, float* __restrict__ Ko, short* __restrict__ Pno,
    short* __restrict__ W2hT_hi, short* __restrict__ WfhT_hi)
{
    __shared__ float smem[16 * 256];   // 16 KB, aliased by both parts

    if (blockIdx.x < 512) {
        // ---- proj: rows row0 .. row0+15 ----
        float (*rowbuf)[256] = (float(*)[256])smem;
        const int row0 = blockIdx.x * 16;
        const int t = threadIdx.x;
        const int wave = t >> 6, lane = t & 63;
        const float* src = act + (size_t)row0 * DD;
        for (int i = t; i < 16 * DD; i += 256) rowbuf[i >> 8][i & 255] = src[i];
        __syncthreads();

        float q[4], k[4], c[4];
        #pragma unroll
        for (int r = 0; r < 4; ++r) { q[r] = bq[lane]; k[r] = bk[lane]; c[r] = bc[lane]; }

        for (int d = 0; d < DD; ++d) {
            float wq = Wq[d * DP + lane];
            float wk = Wk[d * DP + lane];
            float wc = Wc[d * DP + lane];
            #pragma unroll
            for (int r = 0; r < 4; ++r) {
                float av = rowbuf[wave * 4 + r][d];
                q[r] = fmaf(av, wq, q[r]);
                k[r] = fmaf(av, wk, k[r]);
                c[r] = fmaf(av, wc, c[r]);
            }
        }
        #pragma unroll
        for (int r = 0; r < 4; ++r) {
            float ss = c[r] * c[r];
            #pragma unroll
            for (int off = 32; off; off >>= 1) ss += __shfl_xor(ss, off);
            float nrm = fmaxf(sqrtf(ss), 1e-12f);
            size_t o = (size_t)(row0 + wave * 4 + r) * DP + lane;
            Qo[o] = q[r];
            Ko[o] = k[r];
            Pno[o] = f2bf(c[r] / nrm);
        }
    } else {
        // ---- prep: transpose + bf16 hi only ----
        float (*tile)[33] = (float(*)[33])smem;
        int b = blockIdx.x - 512;
        const float* src; short* dhi; int R, C, r0, c0;
        if (b < 512) {               // W2h [256][2048] -> W2hT [2048][256]
            src = W2h; dhi = W2hT_hi; R = 256; C = 2048;
            r0 = (b >> 6) * 32; c0 = (b & 63) * 32;
        } else {                     // Wfh [2048][256] -> WfhT [256][2048]
            b -= 512;
            src = Wfh; dhi = WfhT_hi; R = 2048; C = 256;
            r0 = (b >> 3) * 32; c0 = (b & 7) * 32;
        }
        int tx = threadIdx.x & 31, ty = threadIdx.x >> 5;
        #pragma unroll
        for (int i = 0; i < 4; ++i)
            tile[ty + 8 * i][tx] = src[(size_t)(r0 + ty + 8 * i) * C + c0 + tx];
        __syncthreads();
        #pragma unroll
        for (int i = 0; i < 4; ++i) {
            float v = tile[tx][ty + 8 * i];
            size_t o = (size_t)(c0 + ty + 8 * i) * R + r0 + tx;
            dhi[o] = f2bf(v);
        }
    }
}

// ---------------- Stage 2 (fused): scores + per-wave register top-16 + softmax + gather ----------------
// grid: 8192/8 = 1024 blocks, 512 threads (8 waves). Wave w owns row blockIdx.x*8+w.
__global__ __launch_bounds__(512, 4) void attn_fused_kernel(
    const float* __restrict__ Q, const float* __restrict__ K,
    const float* __restrict__ log_temp,
    const float* __restrict__ states, float* __restrict__ incoming)
{
    const int t = threadIdx.x;
    const int w = t >> 6, l = t & 63;
    const int row = blockIdx.x * 8 + w;
    const int b = row >> 11;

    __shared__ float Ksh[128][68];

    const float temp = fminf(fmaxf(expf(log_temp[0]), 0.1f), 10.0f);
    const float scale = 1.0f / (8.0f * temp);   // SCALE = sqrt(64) = 8

    const float* Kb = K + (size_t)b * NN * DP;
    const float4* qr4 = (const float4*)(Q + (size_t)row * DP);

    float sc[32];

    for (int ch = 0; ch < 16; ++ch) {
        __syncthreads();
        {   // stage 128 K rows (each thread 64B contiguous)
            int r = t >> 2, seg = t & 3;
            const float4* src = (const float4*)(Kb + (size_t)(ch * 128 + r) * DP + seg * 16);
            float4* dst = (float4*)&Ksh[r][seg * 16];
            dst[0] = src[0]; dst[1] = src[1]; dst[2] = src[2]; dst[3] = src[3];
        }
        __syncthreads();
        float a0 = 0.f, a1 = 0.f;
        const float4* k0 = (const float4*)&Ksh[l][0];
        const float4* k1 = (const float4*)&Ksh[64 + l][0];
        #pragma unroll
        for (int h = 0; h < 2; ++h) {
            float4 q[8];
            #pragma unroll
            for (int i = 0; i < 8; ++i) q[i] = qr4[h * 8 + i];
            #pragma unroll
            for (int i = 0; i < 8; ++i) {
                float4 kv0 = k0[h * 8 + i];
                float4 kv1 = k1[h * 8 + i];
                a0 = fmaf(kv0.x, q[i].x, fmaf(kv0.y, q[i].y, fmaf(kv0.z, q[i].z, fmaf(kv0.w, q[i].w, a0))));
                a1 = fmaf(kv1.x, q[i].x, fmaf(kv1.y, q[i].y, fmaf(kv1.z, q[i].z, fmaf(kv1.w, q[i].w, a1))));
            }
        }
        sc[ch * 2]     = a0 * scale;
        sc[ch * 2 + 1] = a1 * scale;
    }

    // per-wave top-16 tournament; slot i of lane l holds m = (i>>1)*128 + (i&1)*64 + l
    float wv = 0.f; int wm = 0;
    for (int it = 0; it < KTOP; ++it) {
        float bv = sc[0]; int bs = 0;
        #pragma unroll
        for (int i = 1; i < 32; ++i) {
            bool g = sc[i] > bv;            // strict > keeps earliest slot (smallest m)
            bv = g ? sc[i] : bv;
            bs = g ? i : bs;
        }
        int bm = (bs >> 1) * 128 + (bs & 1) * 64 + l;
        #pragma unroll
        for (int off = 1; off < 64; off <<= 1) {
            float ov = __shfl_xor(bv, off);
            int   om = __shfl_xor(bm, off);
            bool take = (ov > bv) || (ov == bv && om < bm);
            bv = take ? ov : bv;
            bm = take ? om : bm;
        }
        if (l == it) { wv = bv; wm = bm; }
        if ((bm & 63) == l) {
            int s = ((bm >> 7) << 1) | ((bm >> 6) & 1);
            #pragma unroll
            for (int i = 0; i < 32; ++i) if (s == i) sc[i] = -3.0e38f;
        }
    }

    // softmax over the 16 winners (lanes 0..15 hold them, descending)
    float mx = __shfl(wv, 0);
    float e = (l < KTOP) ? expf(wv - mx) : 0.f;
    float Z = e;
    #pragma unroll
    for (int off = 1; off < 64; off <<= 1) Z += __shfl_xor(Z, off);
    float wnorm = e / Z;                    // lane i<16: normalized weight of winner i

    // fused gather: incoming[row] = sum_k w_k * states[b, idx_k]
    const float* Sb = states + (size_t)b * NN * DD;
    f32x4 acc = (f32x4){0.f, 0.f, 0.f, 0.f};
    #pragma unroll
    for (int kk = 0; kk < KTOP; ++kk) {
        float wk = __shfl(wnorm, kk);
        int   ik = __shfl(wm, kk);
        const float4 v = *(const float4*)(Sb + (size_t)ik * DD + l * 4);
        acc[0] = fmaf(wk, v.x, acc[0]);
        acc[1] = fmaf(wk, v.y, acc[1]);
        acc[2] = fmaf(wk, v.z, acc[2]);
        acc[3] = fmaf(wk, v.w, acc[3]);
    }
    *(float4*)(incoming + (size_t)row * DD + l * 4) = *(float4*)&acc;
}

// ---------------- Stage 3 (MFMA, round-17 proven): sim -> sigmoid -> combined -> mixed -----------
// grid: BATCH*(NN/32)*2 = 512 blocks, 256 threads (4 waves). Block: 32 rows x 128-col d-half.
// incT staged with ds_write_b64 (4 bf16 along m).
__global__ __launch_bounds__(256) void coal_kernel(
    const short* __restrict__ pnb_g, const float* __restrict__ incoming,
    const float* __restrict__ temp_coal, float* __restrict__ mixed)
{
    const int b  = blockIdx.x >> 7;
    const int rem = blockIdx.x & 127;
    const int n0 = (rem >> 1) * 32;
    const int dh = rem & 1;
    const int t = threadIdx.x;
    const int w = t >> 6;
    const int l = t & 63;

    __shared__ alignas(16) short pnA[32][72];
    __shared__ alignas(16) short pnB[64][72];
    __shared__ alignas(16) short cwt[32][72];
    __shared__ alignas(16) short incT[128][72];
    __shared__ float rowsum[32];

    const size_t bbase = (size_t)b * NN;

    {
        int r = t >> 3, k8 = (t & 7) * 8;
        *(short8*)&pnA[r][k8] = *(const short8*)(pnb_g + (bbase + n0 + r) * DP + k8);
    }
    if (t < 32) rowsum[t] = 0.0f;

    const float tc = temp_coal[0];

    f32x4 acc[2][2];
    #pragma unroll
    for (int i = 0; i < 2; ++i)
        #pragma unroll
        for (int j = 0; j < 2; ++j)
            acc[i][j] = (f32x4){0.f, 0.f, 0.f, 0.f};

    const int lrow = l & 15;
    const int lk   = (l >> 4) * 8;

    for (int ch = 0; ch < 32; ++ch) {
        const int m0 = ch * 64;
        __syncthreads();

        {
            int r = t >> 2, kq = (t & 3) * 16;
            const short* src = pnb_g + (bbase + m0 + r) * DP + kq;
            *(short8*)&pnB[r][kq]     = *(const short8*)src;
            *(short8*)&pnB[r][kq + 8] = *(const short8*)(src + 8);
        }
        {   // incT staging: each task = 4m x 4d sub-tile; 4 float4 loads + 4 ds_write_b64
            #pragma unroll
            for (int rep = 0; rep < 2; ++rep) {
                int id = t + rep * 256;
                int mq = id & 15;            // m-quad 0..15
                int dq = id >> 4;            // d-quad 0..31
                const float* incb = incoming + (bbase + m0 + mq * 4) * DD + dh * 128 + dq * 4;
                short4v col0, col1, col2, col3;
                #pragma unroll
                for (int mm = 0; mm < 4; ++mm) {
                    float4 v = *(const float4*)(incb + (size_t)mm * DD);
                    col0[mm] = f2bf(v.x);
                    col1[mm] = f2bf(v.y);
                    col2[mm] = f2bf(v.z);
                    col3[mm] = f2bf(v.w);
                }
                *(short4v*)&incT[dq * 4 + 0][mq * 4] = col0;
                *(short4v*)&incT[dq * 4 + 1][mq * 4] = col1;
                *(short4v*)&incT[dq * 4 + 2][mq * 4] = col2;
                *(short4v*)&incT[dq * 4 + 3][mq * 4] = col3;
            }
        }
        __syncthreads();

        f32x4 sacc[2];
        sacc[0] = (f32x4){0.f, 0.f, 0.f, 0.f};
        sacc[1] = (f32x4){0.f, 0.f, 0.f, 0.f};
        #pragma unroll
        for (int ks = 0; ks < 2; ++ks) {
            short8 bfr = *(const short8*)&pnB[w * 16 + lrow][lk + ks * 32];
            short8 a0  = *(const short8*)&pnA[lrow][lk + ks * 32];
            short8 a1  = *(const short8*)&pnA[16 + lrow][lk + ks * 32];
            sacc[0] = __builtin_amdgcn_mfma_f32_16x16x32_bf16(a0, bfr, sacc[0], 0, 0, 0);
            sacc[1] = __builtin_amdgcn_mfma_f32_16x16x32_bf16(a1, bfr, sacc[1], 0, 0, 0);
        }
        #pragma unroll
        for (int rt = 0; rt < 2; ++rt) {
            #pragma unroll
            for (int j = 0; j < 4; ++j) {
                int rr = rt * 16 + (l >> 4) * 4 + j;
                int cc = w * 16 + lrow;
                float cv = 1.0f / (1.0f + expf(-(sacc[rt][j] - 0.7f) * tc));
                cwt[rr][cc] = f2bf(cv);
            }
        }
        __syncthreads();

        {
            int r = t >> 3, c8 = (t & 7) * 8;
            short8 cv = *(const short8*)&cwt[r][c8];
            float p = 0.f;
            #pragma unroll
            for (int j = 0; j < 8; ++j) p += bf2f(cv[j]);
            p += __shfl_xor(p, 1);
            p += __shfl_xor(p, 2);
            p += __shfl_xor(p, 4);
            if ((t & 7) == 0) rowsum[r] += p;
        }

        #pragma unroll
        for (int ks = 0; ks < 2; ++ks) {
            short8 a0 = *(const short8*)&cwt[lrow][lk + ks * 32];
            short8 a1 = *(const short8*)&cwt[16 + lrow][lk + ks * 32];
            #pragma unroll
            for (int ct = 0; ct < 2; ++ct) {
                short8 bfr = *(const short8*)&incT[w * 32 + ct * 16 + lrow][lk + ks * 32];
                acc[0][ct] = __builtin_amdgcn_mfma_f32_16x16x32_bf16(a0, bfr, acc[0][ct], 0, 0, 0);
                acc[1][ct] = __builtin_amdgcn_mfma_f32_16x16x32_bf16(a1, bfr, acc[1][ct], 0, 0, 0);
            }
        }
    }
    __syncthreads();

    #pragma unroll
    for (int rt = 0; rt < 2; ++rt) {
        #pragma unroll
        for (int ct = 0; ct < 2; ++ct) {
            #pragma unroll
            for (int j = 0; j < 4; ++j) {
                int rr = rt * 16 + (l >> 4) * 4 + j;
                int cc = w * 32 + ct * 16 + lrow;
                float inv = 1.0f / (rowsum[rr] + 1e-8f);
                float comb = acc[rt][ct][j] * inv;
                size_t gi = (bbase + n0 + rr) * DD + dh * 128 + cc;
                mixed[gi] = 0.8f * incoming[gi] + 0.2f * comb;
            }
        }
    }
}

// ---------------- Stage 4a (MFMA): z = mixed@W2h + b2h -> q bits; 2-term split (a_hi+a_lo)*b_hi ---
__global__ __launch_bounds__(256) void hdcA_kernel(
    const float* __restrict__ mixed,
    const short* __restrict__ W2hT_hi,
    const float* __restrict__ b2h,
    unsigned short* __restrict__ qbits)
{
    const int rb = blockIdx.x >> 3;
    const int hs = blockIdx.x & 7;
    const int row0 = rb * 32;
    const int hbase = hs * 256;
    const int t = threadIdx.x;
    const int w = t >> 6, l = t & 63;
    const int lr = l & 15, lg = l >> 4;

    __shared__ short Ahi[32][264], Alo[32][264];
    __shared__ short Whi[64][136];

    #pragma unroll
    for (int i = 0; i < 8; ++i) {
        int idx = t + i * 256;
        int r = idx >> 6, c = (idx & 63) * 4;
        float4 v = *(const float4*)(mixed + (size_t)(row0 + r) * DD + c);
        short4v hi4, lo4;
        hi4[0] = f2bf(v.x); lo4[0] = f2bf(v.x - bf2f(hi4[0]));
        hi4[1] = f2bf(v.y); lo4[1] = f2bf(v.y - bf2f(hi4[1]));
        hi4[2] = f2bf(v.z); lo4[2] = f2bf(v.z - bf2f(hi4[2]));
        hi4[3] = f2bf(v.w); lo4[3] = f2bf(v.w - bf2f(hi4[3]));
        *(short4v*)&Ahi[r][c] = hi4;
        *(short4v*)&Alo[r][c] = lo4;
    }

    for (int ch = 0; ch < 4; ++ch) {
        const int h0 = hbase + ch * 64;
        f32x4 zac[2];
        zac[0] = (f32x4){0.f, 0.f, 0.f, 0.f};
        zac[1] = (f32x4){0.f, 0.f, 0.f, 0.f};
        #pragma unroll
        for (int ks = 0; ks < 2; ++ks) {
            const int k0 = ks * 128;
            __syncthreads();
            {
                int r = t >> 2, cb = (t & 3) * 32;
                const short* sh = W2hT_hi + (size_t)(h0 + r) * DD + k0 + cb;
                #pragma unroll
                for (int j = 0; j < 4; ++j)
                    *(short8*)&Whi[r][cb + j * 8] = *(const short8*)(sh + j * 8);
            }
            __syncthreads();
            #pragma unroll
            for (int kt = 0; kt < 4; ++kt) {
                int kk = k0 + kt * 32 + lg * 8;
                int kw = kt * 32 + lg * 8;
                short8 bhi = *(const short8*)&Whi[w * 16 + lr][kw];
                #pragma unroll
                for (int mt = 0; mt < 2; ++mt) {
                    short8 ahi = *(const short8*)&Ahi[mt * 16 + lr][kk];
                    short8 alo = *(const short8*)&Alo[mt * 16 + lr][kk];
                    zac[mt] = __builtin_amdgcn_mfma_f32_16x16x32_bf16(ahi, bhi, zac[mt], 0, 0, 0);
                    zac[mt] = __builtin_amdgcn_mfma_f32_16x16x32_bf16(alo, bhi, zac[mt], 0, 0, 0);
                }
            }
        }
        const float bv = b2h[h0 + w * 16 + lr];
        #pragma unroll
        for (int mt = 0; mt < 2; ++mt) {
            #pragma unroll
            for (int j = 0; j < 4; ++j) {
                float z = zac[mt][j] + bv;
                unsigned long long bal = __ballot(z >= 0.0f);
                if (lr == 0)
                    qbits[(size_t)(row0 + mt * 16 + lg * 4 + j) * 128 + (h0 >> 4) + w] =
                        (unsigned short)((bal >> (lg * 16)) & 0xFFFFull);
            }
        }
    }
}

// ---------------- Stage 4b (MFMA): nm recompute + num/ns + strength + recall + out ----------------
__global__ __launch_bounds__(512) void hdcB_kernel(
    const float* __restrict__ mem, const unsigned short* __restrict__ qbits,
    const float* __restrict__ pos_codes, const int* __restrict__ step,
    const short* __restrict__ WfhT_hi,
    const float* __restrict__ bfh, const float* __restrict__ keys,
    const float* __restrict__ mixed, float* __restrict__ out)
{
    const int mb = blockIdx.x >> 1, nb = blockIdx.x & 1;
    const int row0 = mb * 32, d0 = nb * 128;
    const int t = threadIdx.x;
    const int w = t >> 6, l = t & 63;
    const int wm = w >> 2, wn = w & 3;
    const int lr = l & 15, lg = l >> 4;

    __shared__ short Ahi[32][72], Alo[32][72];
    __shared__ short Bhi[128][72];
    __shared__ float sred[32][2];
    __shared__ float strenL[32];

    int st = ((step[0] % 256) + 256) % 256;
    const float* pos = pos_codes + (size_t)st * HH;

    f32x4 acc[2];
    acc[0] = (f32x4){0.f, 0.f, 0.f, 0.f};
    acc[1] = (f32x4){0.f, 0.f, 0.f, 0.f};
    float pnum = 0.f, pns = 0.f;

    const int ar = t >> 4;              // row 0..31
    const int ah = (t & 15) * 4;        // h offset within 64-chunk
    const int arow = row0 + ar;
    const size_t memb = (size_t)arow * HH;
    const size_t keyb = (size_t)(arow & (NN - 1)) * HH;

    for (int kc = 0; kc < 32; ++kc) {
        const int h0 = kc * 64;
        __syncthreads();
        {   // A stage: nm recompute + num/ns partials (coalesced float4 loads)
            float4 mv = *(const float4*)(mem + memb + h0 + ah);
            float4 kv = *(const float4*)(keys + keyb + h0 + ah);
            float4 pv = *(const float4*)(pos + h0 + ah);
            unsigned bits = (unsigned)qbits[(size_t)arow * 128 + ((h0 + ah) >> 4)] >> (ah & 15);
            float mvs[4] = { mv.x, mv.y, mv.z, mv.w };
            float kvs[4] = { kv.x, kv.y, kv.z, kv.w };
            float pvs[4] = { pv.x, pv.y, pv.z, pv.w };
            short4v hi4, lo4;
            #pragma unroll
            for (int j = 0; j < 4; ++j) {
                float q = ((bits >> j) & 1u) ? 1.0f : -1.0f;
                float nmv = fmaf(0.05f * q, pvs[j], 0.95f * mvs[j]);
                pnum = fmaf(nmv, q * kvs[j], pnum);
                pns  = fmaf(nmv, nmv, pns);
                hi4[j] = f2bf(nmv);
                lo4[j] = f2bf(nmv - bf2f(hi4[j]));
            }
            *(short4v*)&Ahi[ar][ah] = hi4;
            *(short4v*)&Alo[ar][ah] = lo4;
        }
        {   // B stage: WfhT 128 x 64 (hi only)
            int r = t >> 2, hb = (t & 3) * 16;
            const short* sh = WfhT_hi + (size_t)(d0 + r) * HH + h0 + hb;
            *(short8*)&Bhi[r][hb]     = *(const short8*)sh;
            *(short8*)&Bhi[r][hb + 8] = *(const short8*)(sh + 8);
        }
        __syncthreads();
        #pragma unroll
        for (int kt = 0; kt < 2; ++kt) {
            const int kk = kt * 32 + lg * 8;
            short8 ahi = *(const short8*)&Ahi[wm * 16 + lr][kk];
            short8 alo = *(const short8*)&Alo[wm * 16 + lr][kk];
            #pragma unroll
            for (int nt = 0; nt < 2; ++nt) {
                short8 bhi = *(const short8*)&Bhi[wn * 32 + nt * 16 + lr][kk];
                acc[nt] = __builtin_amdgcn_mfma_f32_16x16x32_bf16(ahi, bhi, acc[nt], 0, 0, 0);
                acc[nt] = __builtin_amdgcn_mfma_f32_16x16x32_bf16(alo, bhi, acc[nt], 0, 0, 0);
            }
        }
    }

    // num/ns: reduce across the 16 threads sharing each row (same wave)
    #pragma unroll
    for (int off = 1; off < 16; off <<= 1) {
        pnum += __shfl_xor(pnum, off);
        pns  += __shfl_xor(pns, off);
    }
    if ((t & 15) == 0) { sred[ar][0] = pnum; sred[ar][1] = pns; }
    __syncthreads();
    if (t < 32) {
        float cosv = sred[t][0] / (fmaxf(sqrtf(sred[t][1]), 1e-8f) * sqrtf(2048.0f));
        strenL[t] = 1.0f / (1.0f + expf(-cosv));
    }
    __syncthreads();

    #pragma unroll
    for (int nt = 0; nt < 2; ++nt) {
        #pragma unroll
        for (int j = 0; j < 4; ++j) {
            int rloc = wm * 16 + lg * 4 + j;
            int col = d0 + wn * 32 + nt * 16 + lr;
            size_t gi = (size_t)(row0 + rloc) * DD + col;
            out[gi] = mixed[gi] + (acc[nt][j] + bfh[col]) * strenL[rloc];
        }
    }
}

extern "C" void kernel_launch(void* const* d_in, const int* in_sizes, int n_in,
                              void* d_out, int out_size, void* d_ws, size_t ws_size,
                              hipStream_t stream) {
    const float* states    = (const float*)d_in[0];
    const float* actions   = (const float*)d_in[1];
    const float* mem       = (const float*)d_in[2];
    const float* Wq        = (const float*)d_in[3];
    const float* bq        = (const float*)d_in[4];
    const float* Wk        = (const float*)d_in[5];
    const float* bk        = (const float*)d_in[6];
    const float* log_temp  = (const float*)d_in[7];
    const float* Wc        = (const float*)d_in[8];
    const float* bc        = (const float*)d_in[9];
    const float* temp_coal = (const float*)d_in[10];
    const float* W2h       = (const float*)d_in[11];
    const float* b2h       = (const float*)d_in[12];
    const float* Wfh       = (const float*)d_in[13];
    const float* bfh       = (const float*)d_in[14];
    const float* keys      = (const float*)d_in[15];
    const float* pos_codes = (const float*)d_in[16];
    const int*   step      = (const int*)d_in[17];
    float* out = (float*)d_out;

    float* ws = (float*)d_ws;
    float* mixed    = ws;                                    // 2,097,152 f32
    short* W2hT_hi  = (short*)(mixed + 2097152);             // 524288 shorts
    short* WfhT_hi  = W2hT_hi + 524288;
    unsigned short* qbits = (unsigned short*)(WfhT_hi + 524288);  // 1,048,576 u16
    float* Q        = (float*)(qbits + 1048576);             // 524288 f32
    float* K        = Q + 524288;
    float* incoming = K + 524288;                            // 2,097,152 f32
    short* pn_bf    = (short*)(incoming + 2097152);          // 524288 shorts

    head_kernel<<<1536, 256, 0, stream>>>(actions, Wq, bq, Wk, bk, Wc, bc, W2h, Wfh,
                                          Q, K, pn_bf, W2hT_hi, WfhT_hi);
    attn_fused_kernel<<<BATCH * NN / 8, 512, 0, stream>>>(Q, K, log_temp, states, incoming);
    coal_kernel<<<BATCH * (NN / 32) * 2, 256, 0, stream>>>(pn_bf, incoming, temp_coal, mixed);
    hdcA_kernel<<<(BATCH * NN / 32) * 8, 256, 0, stream>>>(mixed, W2hT_hi, b2h, qbits);
    hdcB_kernel<<<(BATCH * NN / 32) * 2, 512, 0, stream>>>(mem, qbits, pos_codes, step,
                                                           WfhT_hi, bfh, keys, mixed, out);
}

// Round 20
// 305.793 us; speedup vs baseline: 1.1649x; 1.0171x over previous
//
#include <hip/hip_runtime.h>
#include <math.h>

#define BATCH 4
#define NN 2048
#define DD 256
#define HH 2048
#define DP 64
#define KTOP 16

typedef float f32x4 __attribute__((ext_vector_type(4)));
typedef short short8 __attribute__((ext_vector_type(8)));
typedef short short4v __attribute__((ext_vector_type(4)));

__device__ __forceinline__ short f2bf(float x) {
    union { float f; unsigned u; } v; v.f = x;
    unsigned r = v.u + 0x7FFFu + ((v.u >> 16) & 1u);   // round-to-nearest-even
    return (short)(r >> 16);
}
__device__ __forceinline__ float bf2f(short s) {
    union { unsigned u; float f; } v; v.u = ((unsigned)(unsigned short)s) << 16;
    return v.f;
}

// ---------------- Head: fused proj (blocks 0..511) + weight prep (blocks 512..1535, hi only) -------
__global__ __launch_bounds__(256) void head_kernel(
    const float* __restrict__ act,
    const float* __restrict__ Wq, const float* __restrict__ bq,
    const float* __restrict__ Wk, const float* __restrict__ bk,
    const float* __restrict__ Wc, const float* __restrict__ bc,
    const float* __restrict__ W2h, const float* __restrict__ Wfh,
    float* __restrict__ Qo, float* __restrict__ Ko, short* __restrict__ Pno,
    short* __restrict__ W2hT_hi, short* __restrict__ WfhT_hi)
{
    __shared__ float smem[16 * 256];   // 16 KB, aliased by both parts

    if (blockIdx.x < 512) {
        // ---- proj: rows row0 .. row0+15 ----
        float (*rowbuf)[256] = (float(*)[256])smem;
        const int row0 = blockIdx.x * 16;
        const int t = threadIdx.x;
        const int wave = t >> 6, lane = t & 63;
        const float* src = act + (size_t)row0 * DD;
        for (int i = t; i < 16 * DD; i += 256) rowbuf[i >> 8][i & 255] = src[i];
        __syncthreads();

        float q[4], k[4], c[4];
        #pragma unroll
        for (int r = 0; r < 4; ++r) { q[r] = bq[lane]; k[r] = bk[lane]; c[r] = bc[lane]; }

        for (int d = 0; d < DD; ++d) {
            float wq = Wq[d * DP + lane];
            float wk = Wk[d * DP + lane];
            float wc = Wc[d * DP + lane];
            #pragma unroll
            for (int r = 0; r < 4; ++r) {
                float av = rowbuf[wave * 4 + r][d];
                q[r] = fmaf(av, wq, q[r]);
                k[r] = fmaf(av, wk, k[r]);
                c[r] = fmaf(av, wc, c[r]);
            }
        }
        #pragma unroll
        for (int r = 0; r < 4; ++r) {
            float ss = c[r] * c[r];
            #pragma unroll
            for (int off = 32; off; off >>= 1) ss += __shfl_xor(ss, off);
            float nrm = fmaxf(sqrtf(ss), 1e-12f);
            size_t o = (size_t)(row0 + wave * 4 + r) * DP + lane;
            Qo[o] = q[r];
            Ko[o] = k[r];
            Pno[o] = f2bf(c[r] / nrm);
        }
    } else {
        // ---- prep: transpose + bf16 hi only ----
        float (*tile)[33] = (float(*)[33])smem;
        int b = blockIdx.x - 512;
        const float* src; short* dhi; int R, C, r0, c0;
        if (b < 512) {               // W2h [256][2048] -> W2hT [2048][256]
            src = W2h; dhi = W2hT_hi; R = 256; C = 2048;
            r0 = (b >> 6) * 32; c0 = (b & 63) * 32;
        } else {                     // Wfh [2048][256] -> WfhT [256][2048]
            b -= 512;
            src = Wfh; dhi = WfhT_hi; R = 2048; C = 256;
            r0 = (b >> 3) * 32; c0 = (b & 7) * 32;
        }
        int tx = threadIdx.x & 31, ty = threadIdx.x >> 5;
        #pragma unroll
        for (int i = 0; i < 4; ++i)
            tile[ty + 8 * i][tx] = src[(size_t)(r0 + ty + 8 * i) * C + c0 + tx];
        __syncthreads();
        #pragma unroll
        for (int i = 0; i < 4; ++i) {
            float v = tile[tx][ty + 8 * i];
            size_t o = (size_t)(c0 + ty + 8 * i) * R + r0 + tx;
            dhi[o] = f2bf(v);
        }
    }
}

// ---------------- Stage 2 (fused): scores + per-wave register top-16 + softmax + gather ----------------
// grid: 8192/8 = 1024 blocks, 512 threads (8 waves). Wave w owns row blockIdx.x*8+w.
__global__ __launch_bounds__(512, 4) void attn_fused_kernel(
    const float* __restrict__ Q, const float* __restrict__ K,
    const float* __restrict__ log_temp,
    const float* __restrict__ states, float* __restrict__ incoming)
{
    const int t = threadIdx.x;
    const int w = t >> 6, l = t & 63;
    const int row = blockIdx.x * 8 + w;
    const int b = row >> 11;

    __shared__ float Ksh[128][68];

    const float temp = fminf(fmaxf(expf(log_temp[0]), 0.1f), 10.0f);
    const float scale = 1.0f / (8.0f * temp);   // SCALE = sqrt(64) = 8

    const float* Kb = K + (size_t)b * NN * DP;
    const float4* qr4 = (const float4*)(Q + (size_t)row * DP);

    float sc[32];

    for (int ch = 0; ch < 16; ++ch) {
        __syncthreads();
        {   // stage 128 K rows (each thread 64B contiguous)
            int r = t >> 2, seg = t & 3;
            const float4* src = (const float4*)(Kb + (size_t)(ch * 128 + r) * DP + seg * 16);
            float4* dst = (float4*)&Ksh[r][seg * 16];
            dst[0] = src[0]; dst[1] = src[1]; dst[2] = src[2]; dst[3] = src[3];
        }
        __syncthreads();
        float a0 = 0.f, a1 = 0.f;
        const float4* k0 = (const float4*)&Ksh[l][0];
        const float4* k1 = (const float4*)&Ksh[64 + l][0];
        #pragma unroll
        for (int h = 0; h < 2; ++h) {
            float4 q[8];
            #pragma unroll
            for (int i = 0; i < 8; ++i) q[i] = qr4[h * 8 + i];
            #pragma unroll
            for (int i = 0; i < 8; ++i) {
                float4 kv0 = k0[h * 8 + i];
                float4 kv1 = k1[h * 8 + i];
                a0 = fmaf(kv0.x, q[i].x, fmaf(kv0.y, q[i].y, fmaf(kv0.z, q[i].z, fmaf(kv0.w, q[i].w, a0))));
                a1 = fmaf(kv1.x, q[i].x, fmaf(kv1.y, q[i].y, fmaf(kv1.z, q[i].z, fmaf(kv1.w, q[i].w, a1))));
            }
        }
        sc[ch * 2]     = a0 * scale;
        sc[ch * 2 + 1] = a1 * scale;
    }

    // per-wave top-16 tournament; slot i of lane l holds m = (i>>1)*128 + (i&1)*64 + l
    float wv = 0.f; int wm = 0;
    for (int it = 0; it < KTOP; ++it) {
        float bv = sc[0]; int bs = 0;
        #pragma unroll
        for (int i = 1; i < 32; ++i) {
            bool g = sc[i] > bv;            // strict > keeps earliest slot (smallest m)
            bv = g ? sc[i] : bv;
            bs = g ? i : bs;
        }
        int bm = (bs >> 1) * 128 + (bs & 1) * 64 + l;
        #pragma unroll
        for (int off = 1; off < 64; off <<= 1) {
            float ov = __shfl_xor(bv, off);
            int   om = __shfl_xor(bm, off);
            bool take = (ov > bv) || (ov == bv && om < bm);
            bv = take ? ov : bv;
            bm = take ? om : bm;
        }
        if (l == it) { wv = bv; wm = bm; }
        if ((bm & 63) == l) {
            int s = ((bm >> 7) << 1) | ((bm >> 6) & 1);
            #pragma unroll
            for (int i = 0; i < 32; ++i) if (s == i) sc[i] = -3.0e38f;
        }
    }

    // softmax over the 16 winners (lanes 0..15 hold them, descending)
    float mx = __shfl(wv, 0);
    float e = (l < KTOP) ? expf(wv - mx) : 0.f;
    float Z = e;
    #pragma unroll
    for (int off = 1; off < 64; off <<= 1) Z += __shfl_xor(Z, off);
    float wnorm = e / Z;                    // lane i<16: normalized weight of winner i

    // fused gather: incoming[row] = sum_k w_k * states[b, idx_k]
    const float* Sb = states + (size_t)b * NN * DD;
    f32x4 acc = (f32x4){0.f, 0.f, 0.f, 0.f};
    #pragma unroll
    for (int kk = 0; kk < KTOP; ++kk) {
        float wk = __shfl(wnorm, kk);
        int   ik = __shfl(wm, kk);
        const float4 v = *(const float4*)(Sb + (size_t)ik * DD + l * 4);
        acc[0] = fmaf(wk, v.x, acc[0]);
        acc[1] = fmaf(wk, v.y, acc[1]);
        acc[2] = fmaf(wk, v.z, acc[2]);
        acc[3] = fmaf(wk, v.w, acc[3]);
    }
    *(float4*)(incoming + (size_t)row * DD + l * 4) = *(float4*)&acc;
}

// ---------------- Stage 3 (MFMA, round-17 proven): sim -> sigmoid -> combined -> mixed -----------
__global__ __launch_bounds__(256) void coal_kernel(
    const short* __restrict__ pnb_g, const float* __restrict__ incoming,
    const float* __restrict__ temp_coal, float* __restrict__ mixed)
{
    const int b  = blockIdx.x >> 7;
    const int rem = blockIdx.x & 127;
    const int n0 = (rem >> 1) * 32;
    const int dh = rem & 1;
    const int t = threadIdx.x;
    const int w = t >> 6;
    const int l = t & 63;

    __shared__ alignas(16) short pnA[32][72];
    __shared__ alignas(16) short pnB[64][72];
    __shared__ alignas(16) short cwt[32][72];
    __shared__ alignas(16) short incT[128][72];
    __shared__ float rowsum[32];

    const size_t bbase = (size_t)b * NN;

    {
        int r = t >> 3, k8 = (t & 7) * 8;
        *(short8*)&pnA[r][k8] = *(const short8*)(pnb_g + (bbase + n0 + r) * DP + k8);
    }
    if (t < 32) rowsum[t] = 0.0f;

    const float tc = temp_coal[0];

    f32x4 acc[2][2];
    #pragma unroll
    for (int i = 0; i < 2; ++i)
        #pragma unroll
        for (int j = 0; j < 2; ++j)
            acc[i][j] = (f32x4){0.f, 0.f, 0.f, 0.f};

    const int lrow = l & 15;
    const int lk   = (l >> 4) * 8;

    for (int ch = 0; ch < 32; ++ch) {
        const int m0 = ch * 64;
        __syncthreads();

        {
            int r = t >> 2, kq = (t & 3) * 16;
            const short* src = pnb_g + (bbase + m0 + r) * DP + kq;
            *(short8*)&pnB[r][kq]     = *(const short8*)src;
            *(short8*)&pnB[r][kq + 8] = *(const short8*)(src + 8);
        }
        {   // incT staging: each task = 4m x 4d sub-tile; 4 float4 loads + 4 ds_write_b64
            #pragma unroll
            for (int rep = 0; rep < 2; ++rep) {
                int id = t + rep * 256;
                int mq = id & 15;            // m-quad 0..15
                int dq = id >> 4;            // d-quad 0..31
                const float* incb = incoming + (bbase + m0 + mq * 4) * DD + dh * 128 + dq * 4;
                short4v col0, col1, col2, col3;
                #pragma unroll
                for (int mm = 0; mm < 4; ++mm) {
                    float4 v = *(const float4*)(incb + (size_t)mm * DD);
                    col0[mm] = f2bf(v.x);
                    col1[mm] = f2bf(v.y);
                    col2[mm] = f2bf(v.z);
                    col3[mm] = f2bf(v.w);
                }
                *(short4v*)&incT[dq * 4 + 0][mq * 4] = col0;
                *(short4v*)&incT[dq * 4 + 1][mq * 4] = col1;
                *(short4v*)&incT[dq * 4 + 2][mq * 4] = col2;
                *(short4v*)&incT[dq * 4 + 3][mq * 4] = col3;
            }
        }
        __syncthreads();

        f32x4 sacc[2];
        sacc[0] = (f32x4){0.f, 0.f, 0.f, 0.f};
        sacc[1] = (f32x4){0.f, 0.f, 0.f, 0.f};
        #pragma unroll
        for (int ks = 0; ks < 2; ++ks) {
            short8 bfr = *(const short8*)&pnB[w * 16 + lrow][lk + ks * 32];
            short8 a0  = *(const short8*)&pnA[lrow][lk + ks * 32];
            short8 a1  = *(const short8*)&pnA[16 + lrow][lk + ks * 32];
            sacc[0] = __builtin_amdgcn_mfma_f32_16x16x32_bf16(a0, bfr, sacc[0], 0, 0, 0);
            sacc[1] = __builtin_amdgcn_mfma_f32_16x16x32_bf16(a1, bfr, sacc[1], 0, 0, 0);
        }
        #pragma unroll
        for (int rt = 0; rt < 2; ++rt) {
            #pragma unroll
            for (int j = 0; j < 4; ++j) {
                int rr = rt * 16 + (l >> 4) * 4 + j;
                int cc = w * 16 + lrow;
                float cv = 1.0f / (1.0f + expf(-(sacc[rt][j] - 0.7f) * tc));
                cwt[rr][cc] = f2bf(cv);
            }
        }
        __syncthreads();

        {
            int r = t >> 3, c8 = (t & 7) * 8;
            short8 cv = *(const short8*)&cwt[r][c8];
            float p = 0.f;
            #pragma unroll
            for (int j = 0; j < 8; ++j) p += bf2f(cv[j]);
            p += __shfl_xor(p, 1);
            p += __shfl_xor(p, 2);
            p += __shfl_xor(p, 4);
            if ((t & 7) == 0) rowsum[r] += p;
        }

        #pragma unroll
        for (int ks = 0; ks < 2; ++ks) {
            short8 a0 = *(const short8*)&cwt[lrow][lk + ks * 32];
            short8 a1 = *(const short8*)&cwt[16 + lrow][lk + ks * 32];
            #pragma unroll
            for (int ct = 0; ct < 2; ++ct) {
                short8 bfr = *(const short8*)&incT[w * 32 + ct * 16 + lrow][lk + ks * 32];
                acc[0][ct] = __builtin_amdgcn_mfma_f32_16x16x32_bf16(a0, bfr, acc[0][ct], 0, 0, 0);
                acc[1][ct] = __builtin_amdgcn_mfma_f32_16x16x32_bf16(a1, bfr, acc[1][ct], 0, 0, 0);
            }
        }
    }
    __syncthreads();

    #pragma unroll
    for (int rt = 0; rt < 2; ++rt) {
        #pragma unroll
        for (int ct = 0; ct < 2; ++ct) {
            #pragma unroll
            for (int j = 0; j < 4; ++j) {
                int rr = rt * 16 + (l >> 4) * 4 + j;
                int cc = w * 32 + ct * 16 + lrow;
                float inv = 1.0f / (rowsum[rr] + 1e-8f);
                float comb = acc[rt][ct][j] * inv;
                size_t gi = (bbase + n0 + rr) * DD + dh * 128 + cc;
                mixed[gi] = 0.8f * incoming[gi] + 0.2f * comb;
            }
        }
    }
}

// ---------------- Stage 4a (MFMA): z = mixed@W2h + b2h -> q bits; 2-term split (a_hi+a_lo)*b_hi ---
__global__ __launch_bounds__(256) void hdcA_kernel(
    const float* __restrict__ mixed,
    const short* __restrict__ W2hT_hi,
    const float* __restrict__ b2h,
    unsigned short* __restrict__ qbits)
{
    const int rb = blockIdx.x >> 3;
    const int hs = blockIdx.x & 7;
    const int row0 = rb * 32;
    const int hbase = hs * 256;
    const int t = threadIdx.x;
    const int w = t >> 6, l = t & 63;
    const int lr = l & 15, lg = l >> 4;

    __shared__ short Ahi[32][264], Alo[32][264];
    __shared__ short Whi[64][136];

    #pragma unroll
    for (int i = 0; i < 8; ++i) {
        int idx = t + i * 256;
        int r = idx >> 6, c = (idx & 63) * 4;
        float4 v = *(const float4*)(mixed + (size_t)(row0 + r) * DD + c);
        short4v hi4, lo4;
        hi4[0] = f2bf(v.x); lo4[0] = f2bf(v.x - bf2f(hi4[0]));
        hi4[1] = f2bf(v.y); lo4[1] = f2bf(v.y - bf2f(hi4[1]));
        hi4[2] = f2bf(v.z); lo4[2] = f2bf(v.z - bf2f(hi4[2]));
        hi4[3] = f2bf(v.w); lo4[3] = f2bf(v.w - bf2f(hi4[3]));
        *(short4v*)&Ahi[r][c] = hi4;
        *(short4v*)&Alo[r][c] = lo4;
    }

    for (int ch = 0; ch < 4; ++ch) {
        const int h0 = hbase + ch * 64;
        f32x4 zac[2];
        zac[0] = (f32x4){0.f, 0.f, 0.f, 0.f};
        zac[1] = (f32x4){0.f, 0.f, 0.f, 0.f};
        #pragma unroll
        for (int ks = 0; ks < 2; ++ks) {
            const int k0 = ks * 128;
            __syncthreads();
            {
                int r = t >> 2, cb = (t & 3) * 32;
                const short* sh = W2hT_hi + (size_t)(h0 + r) * DD + k0 + cb;
                #pragma unroll
                for (int j = 0; j < 4; ++j)
                    *(short8*)&Whi[r][cb + j * 8] = *(const short8*)(sh + j * 8);
            }
            __syncthreads();
            #pragma unroll
            for (int kt = 0; kt < 4; ++kt) {
                int kk = k0 + kt * 32 + lg * 8;
                int kw = kt * 32 + lg * 8;
                short8 bhi = *(const short8*)&Whi[w * 16 + lr][kw];
                #pragma unroll
                for (int mt = 0; mt < 2; ++mt) {
                    short8 ahi = *(const short8*)&Ahi[mt * 16 + lr][kk];
                    short8 alo = *(const short8*)&Alo[mt * 16 + lr][kk];
                    zac[mt] = __builtin_amdgcn_mfma_f32_16x16x32_bf16(ahi, bhi, zac[mt], 0, 0, 0);
                    zac[mt] = __builtin_amdgcn_mfma_f32_16x16x32_bf16(alo, bhi, zac[mt], 0, 0, 0);
                }
            }
        }
        const float bv = b2h[h0 + w * 16 + lr];
        #pragma unroll
        for (int mt = 0; mt < 2; ++mt) {
            #pragma unroll
            for (int j = 0; j < 4; ++j) {
                float z = zac[mt][j] + bv;
                unsigned long long bal = __ballot(z >= 0.0f);
                if (lr == 0)
                    qbits[(size_t)(row0 + mt * 16 + lg * 4 + j) * 128 + (h0 >> 4) + w] =
                        (unsigned short)((bal >> (lg * 16)) & 0xFFFFull);
            }
        }
    }
}

// ---------------- Stage 4b (MFMA): nm recompute + num/ns + strength + recall + out ----------------
// recall now 1-term (a_hi * b_hi): dropped alo MFMA (error ~1e-3 << 0.049 threshold).
__global__ __launch_bounds__(512) void hdcB_kernel(
    const float* __restrict__ mem, const unsigned short* __restrict__ qbits,
    const float* __restrict__ pos_codes, const int* __restrict__ step,
    const short* __restrict__ WfhT_hi,
    const float* __restrict__ bfh, const float* __restrict__ keys,
    const float* __restrict__ mixed, float* __restrict__ out)
{
    const int mb = blockIdx.x >> 1, nb = blockIdx.x & 1;
    const int row0 = mb * 32, d0 = nb * 128;
    const int t = threadIdx.x;
    const int w = t >> 6, l = t & 63;
    const int wm = w >> 2, wn = w & 3;
    const int lr = l & 15, lg = l >> 4;

    __shared__ short Ahi[32][72];
    __shared__ short Bhi[128][72];
    __shared__ float sred[32][2];
    __shared__ float strenL[32];

    int st = ((step[0] % 256) + 256) % 256;
    const float* pos = pos_codes + (size_t)st * HH;

    f32x4 acc[2];
    acc[0] = (f32x4){0.f, 0.f, 0.f, 0.f};
    acc[1] = (f32x4){0.f, 0.f, 0.f, 0.f};
    float pnum = 0.f, pns = 0.f;

    const int ar = t >> 4;              // row 0..31
    const int ah = (t & 15) * 4;        // h offset within 64-chunk
    const int arow = row0 + ar;
    const size_t memb = (size_t)arow * HH;
    const size_t keyb = (size_t)(arow & (NN - 1)) * HH;

    for (int kc = 0; kc < 32; ++kc) {
        const int h0 = kc * 64;
        __syncthreads();
        {   // A stage: nm recompute + num/ns partials (coalesced float4 loads)
            float4 mv = *(const float4*)(mem + memb + h0 + ah);
            float4 kv = *(const float4*)(keys + keyb + h0 + ah);
            float4 pv = *(const float4*)(pos + h0 + ah);
            unsigned bits = (unsigned)qbits[(size_t)arow * 128 + ((h0 + ah) >> 4)] >> (ah & 15);
            float mvs[4] = { mv.x, mv.y, mv.z, mv.w };
            float kvs[4] = { kv.x, kv.y, kv.z, kv.w };
            float pvs[4] = { pv.x, pv.y, pv.z, pv.w };
            short4v hi4;
            #pragma unroll
            for (int j = 0; j < 4; ++j) {
                float q = ((bits >> j) & 1u) ? 1.0f : -1.0f;
                float nmv = fmaf(0.05f * q, pvs[j], 0.95f * mvs[j]);
                pnum = fmaf(nmv, q * kvs[j], pnum);
                pns  = fmaf(nmv, nmv, pns);
                hi4[j] = f2bf(nmv);
            }
            *(short4v*)&Ahi[ar][ah] = hi4;
        }
        {   // B stage: WfhT 128 x 64 (hi only)
            int r = t >> 2, hb = (t & 3) * 16;
            const short* sh = WfhT_hi + (size_t)(d0 + r) * HH + h0 + hb;
            *(short8*)&Bhi[r][hb]     = *(const short8*)sh;
            *(short8*)&Bhi[r][hb + 8] = *(const short8*)(sh + 8);
        }
        __syncthreads();
        #pragma unroll
        for (int kt = 0; kt < 2; ++kt) {
            const int kk = kt * 32 + lg * 8;
            short8 ahi = *(const short8*)&Ahi[wm * 16 + lr][kk];
            #pragma unroll
            for (int nt = 0; nt < 2; ++nt) {
                short8 bhi = *(const short8*)&Bhi[wn * 32 + nt * 16 + lr][kk];
                acc[nt] = __builtin_amdgcn_mfma_f32_16x16x32_bf16(ahi, bhi, acc[nt], 0, 0, 0);
            }
        }
    }

    // num/ns: reduce across the 16 threads sharing each row (same wave)
    #pragma unroll
    for (int off = 1; off < 16; off <<= 1) {
        pnum += __shfl_xor(pnum, off);
        pns  += __shfl_xor(pns, off);
    }
    if ((t & 15) == 0) { sred[ar][0] = pnum; sred[ar][1] = pns; }
    __syncthreads();
    if (t < 32) {
        float cosv = sred[t][0] / (fmaxf(sqrtf(sred[t][1]), 1e-8f) * sqrtf(2048.0f));
        strenL[t] = 1.0f / (1.0f + expf(-cosv));
    }
    __syncthreads();

    #pragma unroll
    for (int nt = 0; nt < 2; ++nt) {
        #pragma unroll
        for (int j = 0; j < 4; ++j) {
            int rloc = wm * 16 + lg * 4 + j;
            int col = d0 + wn * 32 + nt * 16 + lr;
            size_t gi = (size_t)(row0 + rloc) * DD + col;
            out[gi] = mixed[gi] + (acc[nt][j] + bfh[col]) * strenL[rloc];
        }
    }
}

extern "C" void kernel_launch(void* const* d_in, const int* in_sizes, int n_in,
                              void* d_out, int out_size, void* d_ws, size_t ws_size,
                              hipStream_t stream) {
    const float* states    = (const float*)d_in[0];
    const float* actions   = (const float*)d_in[1];
    const float* mem       = (const float*)d_in[2];
    const float* Wq        = (const float*)d_in[3];
    const float* bq        = (const float*)d_in[4];
    const float* Wk        = (const float*)d_in[5];
    const float* bk        = (const float*)d_in[6];
    const float* log_temp  = (const float*)d_in[7];
    const float* Wc        = (const float*)d_in[8];
    const float* bc        = (const float*)d_in[9];
    const float* temp_coal = (const float*)d_in[10];
    const float* W2h       = (const float*)d_in[11];
    const float* b2h       = (const float*)d_in[12];
    const float* Wfh       = (const float*)d_in[13];
    const float* bfh       = (const float*)d_in[14];
    const float* keys      = (const float*)d_in[15];
    const float* pos_codes = (const float*)d_in[16];
    const int*   step      = (const int*)d_in[17];
    float* out = (float*)d_out;

    float* ws = (float*)d_ws;
    float* mixed    = ws;                                    // 2,097,152 f32
    short* W2hT_hi  = (short*)(mixed + 2097152);             // 524288 shorts
    short* WfhT_hi  = W2hT_hi + 524288;
    unsigned short* qbits = (unsigned short*)(WfhT_hi + 524288);  // 1,048,576 u16
    float* Q        = (float*)(qbits + 1048576);             // 524288 f32
    float* K        = Q + 524288;
    float* incoming = K + 524288;                            // 2,097,152 f32
    short* pn_bf    = (short*)(incoming + 2097152);          // 524288 shorts

    head_kernel<<<1536, 256, 0, stream>>>(actions, Wq, bq, Wk, bk, Wc, bc, W2h, Wfh,
                                          Q, K, pn_bf, W2hT_hi, WfhT_hi);
    attn_fused_kernel<<<BATCH * NN / 8, 512, 0, stream>>>(Q, K, log_temp, states, incoming);
    coal_kernel<<<BATCH * (NN / 32) * 2, 256, 0, stream>>>(pn_bf, incoming, temp_coal, mixed);
    hdcA_kernel<<<(BATCH * NN / 32) * 8, 256, 0, stream>>>(mixed, W2hT_hi, b2h, qbits);
    hdcB_kernel<<<(BATCH * NN / 32) * 2, 512, 0, stream>>>(mem, qbits, pos_codes, step,
                                                           WfhT_hi, bfh, keys, mixed, out);
}

// Round 21
// 297.251 us; speedup vs baseline: 1.1983x; 1.0287x over previous
//
#include <hip/hip_runtime.h>
#include <math.h>

#define BATCH 4
#define NN 2048
#define DD 256
#define HH 2048
#define DP 64
#define KTOP 16

typedef float f32x4 __attribute__((ext_vector_type(4)));
typedef short short8 __attribute__((ext_vector_type(8)));
typedef short short4v __attribute__((ext_vector_type(4)));

__device__ __forceinline__ short f2bf(float x) {
    union { float f; unsigned u; } v; v.f = x;
    unsigned r = v.u + 0x7FFFu + ((v.u >> 16) & 1u);   // round-to-nearest-even
    return (short)(r >> 16);
}
__device__ __forceinline__ float bf2f(short s) {
    union { unsigned u; float f; } v; v.u = ((unsigned)(unsigned short)s) << 16;
    return v.f;
}

// ---------------- Head: fused proj (blocks 0..511) + weight prep (blocks 512..1535, hi only) -------
__global__ __launch_bounds__(256) void head_kernel(
    const float* __restrict__ act,
    const float* __restrict__ Wq, const float* __restrict__ bq,
    const float* __restrict__ Wk, const float* __restrict__ bk,
    const float* __restrict__ Wc, const float* __restrict__ bc,
    const float* __restrict__ W2h, const float* __restrict__ Wfh,
    float* __restrict__ Qo, float* __restrict__ Ko, short* __restrict__ Pno,
    short* __restrict__ W2hT_hi, short* __restrict__ WfhT_hi)
{
    __shared__ float smem[16 * 256];   // 16 KB, aliased by both parts

    if (blockIdx.x < 512) {
        // ---- proj: rows row0 .. row0+15 ----
        float (*rowbuf)[256] = (float(*)[256])smem;
        const int row0 = blockIdx.x * 16;
        const int t = threadIdx.x;
        const int wave = t >> 6, lane = t & 63;
        const float* src = act + (size_t)row0 * DD;
        for (int i = t; i < 16 * DD; i += 256) rowbuf[i >> 8][i & 255] = src[i];
        __syncthreads();

        float q[4], k[4], c[4];
        #pragma unroll
        for (int r = 0; r < 4; ++r) { q[r] = bq[lane]; k[r] = bk[lane]; c[r] = bc[lane]; }

        for (int d = 0; d < DD; ++d) {
            float wq = Wq[d * DP + lane];
            float wk = Wk[d * DP + lane];
            float wc = Wc[d * DP + lane];
            #pragma unroll
            for (int r = 0; r < 4; ++r) {
                float av = rowbuf[wave * 4 + r][d];
                q[r] = fmaf(av, wq, q[r]);
                k[r] = fmaf(av, wk, k[r]);
                c[r] = fmaf(av, wc, c[r]);
            }
        }
        #pragma unroll
        for (int r = 0; r < 4; ++r) {
            float ss = c[r] * c[r];
            #pragma unroll
            for (int off = 32; off; off >>= 1) ss += __shfl_xor(ss, off);
            float nrm = fmaxf(sqrtf(ss), 1e-12f);
            size_t o = (size_t)(row0 + wave * 4 + r) * DP + lane;
            Qo[o] = q[r];
            Ko[o] = k[r];
            Pno[o] = f2bf(c[r] / nrm);
        }
    } else {
        // ---- prep: transpose + bf16 hi only ----
        float (*tile)[33] = (float(*)[33])smem;
        int b = blockIdx.x - 512;
        const float* src; short* dhi; int R, C, r0, c0;
        if (b < 512) {               // W2h [256][2048] -> W2hT [2048][256]
            src = W2h; dhi = W2hT_hi; R = 256; C = 2048;
            r0 = (b >> 6) * 32; c0 = (b & 63) * 32;
        } else {                     // Wfh [2048][256] -> WfhT [256][2048]
            b -= 512;
            src = Wfh; dhi = WfhT_hi; R = 2048; C = 256;
            r0 = (b >> 3) * 32; c0 = (b & 7) * 32;
        }
        int tx = threadIdx.x & 31, ty = threadIdx.x >> 5;
        #pragma unroll
        for (int i = 0; i < 4; ++i)
            tile[ty + 8 * i][tx] = src[(size_t)(r0 + ty + 8 * i) * C + c0 + tx];
        __syncthreads();
        #pragma unroll
        for (int i = 0; i < 4; ++i) {
            float v = tile[tx][ty + 8 * i];
            size_t o = (size_t)(c0 + ty + 8 * i) * R + r0 + tx;
            dhi[o] = f2bf(v);
        }
    }
}

// ---------------- Stage 2 (fused): scores + per-wave register top-16 + softmax + gather ----------------
// grid: 8192/8 = 1024 blocks, 512 threads (8 waves). Wave w owns row blockIdx.x*8+w.
__global__ __launch_bounds__(512, 4) void attn_fused_kernel(
    const float* __restrict__ Q, const float* __restrict__ K,
    const float* __restrict__ log_temp,
    const float* __restrict__ states, float* __restrict__ incoming)
{
    const int t = threadIdx.x;
    const int w = t >> 6, l = t & 63;
    const int row = blockIdx.x * 8 + w;
    const int b = row >> 11;

    __shared__ float Ksh[128][68];

    const float temp = fminf(fmaxf(expf(log_temp[0]), 0.1f), 10.0f);
    const float scale = 1.0f / (8.0f * temp);   // SCALE = sqrt(64) = 8

    const float* Kb = K + (size_t)b * NN * DP;
    const float4* qr4 = (const float4*)(Q + (size_t)row * DP);

    float sc[32];

    for (int ch = 0; ch < 16; ++ch) {
        __syncthreads();
        {   // stage 128 K rows (each thread 64B contiguous)
            int r = t >> 2, seg = t & 3;
            const float4* src = (const float4*)(Kb + (size_t)(ch * 128 + r) * DP + seg * 16);
            float4* dst = (float4*)&Ksh[r][seg * 16];
            dst[0] = src[0]; dst[1] = src[1]; dst[2] = src[2]; dst[3] = src[3];
        }
        __syncthreads();
        float a0 = 0.f, a1 = 0.f;
        const float4* k0 = (const float4*)&Ksh[l][0];
        const float4* k1 = (const float4*)&Ksh[64 + l][0];
        #pragma unroll
        for (int h = 0; h < 2; ++h) {
            float4 q[8];
            #pragma unroll
            for (int i = 0; i < 8; ++i) q[i] = qr4[h * 8 + i];
            #pragma unroll
            for (int i = 0; i < 8; ++i) {
                float4 kv0 = k0[h * 8 + i];
                float4 kv1 = k1[h * 8 + i];
                a0 = fmaf(kv0.x, q[i].x, fmaf(kv0.y, q[i].y, fmaf(kv0.z, q[i].z, fmaf(kv0.w, q[i].w, a0))));
                a1 = fmaf(kv1.x, q[i].x, fmaf(kv1.y, q[i].y, fmaf(kv1.z, q[i].z, fmaf(kv1.w, q[i].w, a1))));
            }
        }
        sc[ch * 2]     = a0 * scale;
        sc[ch * 2 + 1] = a1 * scale;
    }

    // per-wave top-16 tournament; slot i of lane l holds m = (i>>1)*128 + (i&1)*64 + l
    float wv = 0.f; int wm = 0;
    for (int it = 0; it < KTOP; ++it) {
        float bv = sc[0]; int bs = 0;
        #pragma unroll
        for (int i = 1; i < 32; ++i) {
            bool g = sc[i] > bv;            // strict > keeps earliest slot (smallest m)
            bv = g ? sc[i] : bv;
            bs = g ? i : bs;
        }
        int bm = (bs >> 1) * 128 + (bs & 1) * 64 + l;
        #pragma unroll
        for (int off = 1; off < 64; off <<= 1) {
            float ov = __shfl_xor(bv, off);
            int   om = __shfl_xor(bm, off);
            bool take = (ov > bv) || (ov == bv && om < bm);
            bv = take ? ov : bv;
            bm = take ? om : bm;
        }
        if (l == it) { wv = bv; wm = bm; }
        if ((bm & 63) == l) {
            int s = ((bm >> 7) << 1) | ((bm >> 6) & 1);
            #pragma unroll
            for (int i = 0; i < 32; ++i) if (s == i) sc[i] = -3.0e38f;
        }
    }

    // softmax over the 16 winners (lanes 0..15 hold them, descending)
    float mx = __shfl(wv, 0);
    float e = (l < KTOP) ? expf(wv - mx) : 0.f;
    float Z = e;
    #pragma unroll
    for (int off = 1; off < 64; off <<= 1) Z += __shfl_xor(Z, off);
    float wnorm = e / Z;                    // lane i<16: normalized weight of winner i

    // fused gather: incoming[row] = sum_k w_k * states[b, idx_k]
    const float* Sb = states + (size_t)b * NN * DD;
    f32x4 acc = (f32x4){0.f, 0.f, 0.f, 0.f};
    #pragma unroll
    for (int kk = 0; kk < KTOP; ++kk) {
        float wk = __shfl(wnorm, kk);
        int   ik = __shfl(wm, kk);
        const float4 v = *(const float4*)(Sb + (size_t)ik * DD + l * 4);
        acc[0] = fmaf(wk, v.x, acc[0]);
        acc[1] = fmaf(wk, v.y, acc[1]);
        acc[2] = fmaf(wk, v.z, acc[2]);
        acc[3] = fmaf(wk, v.w, acc[3]);
    }
    *(float4*)(incoming + (size_t)row * DD + l * 4) = *(float4*)&acc;
}

// ---------------- Stage 3 (MFMA, round-17 proven): sim -> sigmoid -> combined -> mixed -----------
__global__ __launch_bounds__(256) void coal_kernel(
    const short* __restrict__ pnb_g, const float* __restrict__ incoming,
    const float* __restrict__ temp_coal, float* __restrict__ mixed)
{
    const int b  = blockIdx.x >> 7;
    const int rem = blockIdx.x & 127;
    const int n0 = (rem >> 1) * 32;
    const int dh = rem & 1;
    const int t = threadIdx.x;
    const int w = t >> 6;
    const int l = t & 63;

    __shared__ alignas(16) short pnA[32][72];
    __shared__ alignas(16) short pnB[64][72];
    __shared__ alignas(16) short cwt[32][72];
    __shared__ alignas(16) short incT[128][72];
    __shared__ float rowsum[32];

    const size_t bbase = (size_t)b * NN;

    {
        int r = t >> 3, k8 = (t & 7) * 8;
        *(short8*)&pnA[r][k8] = *(const short8*)(pnb_g + (bbase + n0 + r) * DP + k8);
    }
    if (t < 32) rowsum[t] = 0.0f;

    const float tc = temp_coal[0];

    f32x4 acc[2][2];
    #pragma unroll
    for (int i = 0; i < 2; ++i)
        #pragma unroll
        for (int j = 0; j < 2; ++j)
            acc[i][j] = (f32x4){0.f, 0.f, 0.f, 0.f};

    const int lrow = l & 15;
    const int lk   = (l >> 4) * 8;

    for (int ch = 0; ch < 32; ++ch) {
        const int m0 = ch * 64;
        __syncthreads();

        {
            int r = t >> 2, kq = (t & 3) * 16;
            const short* src = pnb_g + (bbase + m0 + r) * DP + kq;
            *(short8*)&pnB[r][kq]     = *(const short8*)src;
            *(short8*)&pnB[r][kq + 8] = *(const short8*)(src + 8);
        }
        {   // incT staging: each task = 4m x 4d sub-tile; 4 float4 loads + 4 ds_write_b64
            #pragma unroll
            for (int rep = 0; rep < 2; ++rep) {
                int id = t + rep * 256;
                int mq = id & 15;            // m-quad 0..15
                int dq = id >> 4;            // d-quad 0..31
                const float* incb = incoming + (bbase + m0 + mq * 4) * DD + dh * 128 + dq * 4;
                short4v col0, col1, col2, col3;
                #pragma unroll
                for (int mm = 0; mm < 4; ++mm) {
                    float4 v = *(const float4*)(incb + (size_t)mm * DD);
                    col0[mm] = f2bf(v.x);
                    col1[mm] = f2bf(v.y);
                    col2[mm] = f2bf(v.z);
                    col3[mm] = f2bf(v.w);
                }
                *(short4v*)&incT[dq * 4 + 0][mq * 4] = col0;
                *(short4v*)&incT[dq * 4 + 1][mq * 4] = col1;
                *(short4v*)&incT[dq * 4 + 2][mq * 4] = col2;
                *(short4v*)&incT[dq * 4 + 3][mq * 4] = col3;
            }
        }
        __syncthreads();

        f32x4 sacc[2];
        sacc[0] = (f32x4){0.f, 0.f, 0.f, 0.f};
        sacc[1] = (f32x4){0.f, 0.f, 0.f, 0.f};
        #pragma unroll
        for (int ks = 0; ks < 2; ++ks) {
            short8 bfr = *(const short8*)&pnB[w * 16 + lrow][lk + ks * 32];
            short8 a0  = *(const short8*)&pnA[lrow][lk + ks * 32];
            short8 a1  = *(const short8*)&pnA[16 + lrow][lk + ks * 32];
            sacc[0] = __builtin_amdgcn_mfma_f32_16x16x32_bf16(a0, bfr, sacc[0], 0, 0, 0);
            sacc[1] = __builtin_amdgcn_mfma_f32_16x16x32_bf16(a1, bfr, sacc[1], 0, 0, 0);
        }
        #pragma unroll
        for (int rt = 0; rt < 2; ++rt) {
            #pragma unroll
            for (int j = 0; j < 4; ++j) {
                int rr = rt * 16 + (l >> 4) * 4 + j;
                int cc = w * 16 + lrow;
                float cv = 1.0f / (1.0f + expf(-(sacc[rt][j] - 0.7f) * tc));
                cwt[rr][cc] = f2bf(cv);
            }
        }
        __syncthreads();

        {
            int r = t >> 3, c8 = (t & 7) * 8;
            short8 cv = *(const short8*)&cwt[r][c8];
            float p = 0.f;
            #pragma unroll
            for (int j = 0; j < 8; ++j) p += bf2f(cv[j]);
            p += __shfl_xor(p, 1);
            p += __shfl_xor(p, 2);
            p += __shfl_xor(p, 4);
            if ((t & 7) == 0) rowsum[r] += p;
        }

        #pragma unroll
        for (int ks = 0; ks < 2; ++ks) {
            short8 a0 = *(const short8*)&cwt[lrow][lk + ks * 32];
            short8 a1 = *(const short8*)&cwt[16 + lrow][lk + ks * 32];
            #pragma unroll
            for (int ct = 0; ct < 2; ++ct) {
                short8 bfr = *(const short8*)&incT[w * 32 + ct * 16 + lrow][lk + ks * 32];
                acc[0][ct] = __builtin_amdgcn_mfma_f32_16x16x32_bf16(a0, bfr, acc[0][ct], 0, 0, 0);
                acc[1][ct] = __builtin_amdgcn_mfma_f32_16x16x32_bf16(a1, bfr, acc[1][ct], 0, 0, 0);
            }
        }
    }
    __syncthreads();

    #pragma unroll
    for (int rt = 0; rt < 2; ++rt) {
        #pragma unroll
        for (int ct = 0; ct < 2; ++ct) {
            #pragma unroll
            for (int j = 0; j < 4; ++j) {
                int rr = rt * 16 + (l >> 4) * 4 + j;
                int cc = w * 32 + ct * 16 + lrow;
                float inv = 1.0f / (rowsum[rr] + 1e-8f);
                float comb = acc[rt][ct][j] * inv;
                size_t gi = (bbase + n0 + rr) * DD + dh * 128 + cc;
                mixed[gi] = 0.8f * incoming[gi] + 0.2f * comb;
            }
        }
    }
}

// ---------------- Stage 4a (MFMA): z = mixed@W2h + b2h -> q bits; 1-term (a_hi * b_hi) ------------
__global__ __launch_bounds__(256) void hdcA_kernel(
    const float* __restrict__ mixed,
    const short* __restrict__ W2hT_hi,
    const float* __restrict__ b2h,
    unsigned short* __restrict__ qbits)
{
    const int rb = blockIdx.x >> 3;
    const int hs = blockIdx.x & 7;
    const int row0 = rb * 32;
    const int hbase = hs * 256;
    const int t = threadIdx.x;
    const int w = t >> 6, l = t & 63;
    const int lr = l & 15, lg = l >> 4;

    __shared__ short Ahi[32][264];
    __shared__ short Whi[64][136];

    #pragma unroll
    for (int i = 0; i < 8; ++i) {
        int idx = t + i * 256;
        int r = idx >> 6, c = (idx & 63) * 4;
        float4 v = *(const float4*)(mixed + (size_t)(row0 + r) * DD + c);
        short4v hi4;
        hi4[0] = f2bf(v.x);
        hi4[1] = f2bf(v.y);
        hi4[2] = f2bf(v.z);
        hi4[3] = f2bf(v.w);
        *(short4v*)&Ahi[r][c] = hi4;
    }

    for (int ch = 0; ch < 4; ++ch) {
        const int h0 = hbase + ch * 64;
        f32x4 zac[2];
        zac[0] = (f32x4){0.f, 0.f, 0.f, 0.f};
        zac[1] = (f32x4){0.f, 0.f, 0.f, 0.f};
        #pragma unroll
        for (int ks = 0; ks < 2; ++ks) {
            const int k0 = ks * 128;
            __syncthreads();
            {
                int r = t >> 2, cb = (t & 3) * 32;
                const short* sh = W2hT_hi + (size_t)(h0 + r) * DD + k0 + cb;
                #pragma unroll
                for (int j = 0; j < 4; ++j)
                    *(short8*)&Whi[r][cb + j * 8] = *(const short8*)(sh + j * 8);
            }
            __syncthreads();
            #pragma unroll
            for (int kt = 0; kt < 4; ++kt) {
                int kk = k0 + kt * 32 + lg * 8;
                int kw = kt * 32 + lg * 8;
                short8 bhi = *(const short8*)&Whi[w * 16 + lr][kw];
                #pragma unroll
                for (int mt = 0; mt < 2; ++mt) {
                    short8 ahi = *(const short8*)&Ahi[mt * 16 + lr][kk];
                    zac[mt] = __builtin_amdgcn_mfma_f32_16x16x32_bf16(ahi, bhi, zac[mt], 0, 0, 0);
                }
            }
        }
        const float bv = b2h[h0 + w * 16 + lr];
        #pragma unroll
        for (int mt = 0; mt < 2; ++mt) {
            #pragma unroll
            for (int j = 0; j < 4; ++j) {
                float z = zac[mt][j] + bv;
                unsigned long long bal = __ballot(z >= 0.0f);
                if (lr == 0)
                    qbits[(size_t)(row0 + mt * 16 + lg * 4 + j) * 128 + (h0 >> 4) + w] =
                        (unsigned short)((bal >> (lg * 16)) & 0xFFFFull);
            }
        }
    }
}

// ---------------- Stage 4b (MFMA): nm recompute + num/ns + strength + recall + out ----------------
// recall 1-term (a_hi * b_hi).
__global__ __launch_bounds__(512) void hdcB_kernel(
    const float* __restrict__ mem, const unsigned short* __restrict__ qbits,
    const float* __restrict__ pos_codes, const int* __restrict__ step,
    const short* __restrict__ WfhT_hi,
    const float* __restrict__ bfh, const float* __restrict__ keys,
    const float* __restrict__ mixed, float* __restrict__ out)
{
    const int mb = blockIdx.x >> 1, nb = blockIdx.x & 1;
    const int row0 = mb * 32, d0 = nb * 128;
    const int t = threadIdx.x;
    const int w = t >> 6, l = t & 63;
    const int wm = w >> 2, wn = w & 3;
    const int lr = l & 15, lg = l >> 4;

    __shared__ short Ahi[32][72];
    __shared__ short Bhi[128][72];
    __shared__ float sred[32][2];
    __shared__ float strenL[32];

    int st = ((step[0] % 256) + 256) % 256;
    const float* pos = pos_codes + (size_t)st * HH;

    f32x4 acc[2];
    acc[0] = (f32x4){0.f, 0.f, 0.f, 0.f};
    acc[1] = (f32x4){0.f, 0.f, 0.f, 0.f};
    float pnum = 0.f, pns = 0.f;

    const int ar = t >> 4;              // row 0..31
    const int ah = (t & 15) * 4;        // h offset within 64-chunk
    const int arow = row0 + ar;
    const size_t memb = (size_t)arow * HH;
    const size_t keyb = (size_t)(arow & (NN - 1)) * HH;

    for (int kc = 0; kc < 32; ++kc) {
        const int h0 = kc * 64;
        __syncthreads();
        {   // A stage: nm recompute + num/ns partials (coalesced float4 loads)
            float4 mv = *(const float4*)(mem + memb + h0 + ah);
            float4 kv = *(const float4*)(keys + keyb + h0 + ah);
            float4 pv = *(const float4*)(pos + h0 + ah);
            unsigned bits = (unsigned)qbits[(size_t)arow * 128 + ((h0 + ah) >> 4)] >> (ah & 15);
            float mvs[4] = { mv.x, mv.y, mv.z, mv.w };
            float kvs[4] = { kv.x, kv.y, kv.z, kv.w };
            float pvs[4] = { pv.x, pv.y, pv.z, pv.w };
            short4v hi4;
            #pragma unroll
            for (int j = 0; j < 4; ++j) {
                float q = ((bits >> j) & 1u) ? 1.0f : -1.0f;
                float nmv = fmaf(0.05f * q, pvs[j], 0.95f * mvs[j]);
                pnum = fmaf(nmv, q * kvs[j], pnum);
                pns  = fmaf(nmv, nmv, pns);
                hi4[j] = f2bf(nmv);
            }
            *(short4v*)&Ahi[ar][ah] = hi4;
        }
        {   // B stage: WfhT 128 x 64 (hi only)
            int r = t >> 2, hb = (t & 3) * 16;
            const short* sh = WfhT_hi + (size_t)(d0 + r) * HH + h0 + hb;
            *(short8*)&Bhi[r][hb]     = *(const short8*)sh;
            *(short8*)&Bhi[r][hb + 8] = *(const short8*)(sh + 8);
        }
        __syncthreads();
        #pragma unroll
        for (int kt = 0; kt < 2; ++kt) {
            const int kk = kt * 32 + lg * 8;
            short8 ahi = *(const short8*)&Ahi[wm * 16 + lr][kk];
            #pragma unroll
            for (int nt = 0; nt < 2; ++nt) {
                short8 bhi = *(const short8*)&Bhi[wn * 32 + nt * 16 + lr][kk];
                acc[nt] = __builtin_amdgcn_mfma_f32_16x16x32_bf16(ahi, bhi, acc[nt], 0, 0, 0);
            }
        }
    }

    // num/ns: reduce across the 16 threads sharing each row (same wave)
    #pragma unroll
    for (int off = 1; off < 16; off <<= 1) {
        pnum += __shfl_xor(pnum, off);
        pns  += __shfl_xor(pns, off);
    }
    if ((t & 15) == 0) { sred[ar][0] = pnum; sred[ar][1] = pns; }
    __syncthreads();
    if (t < 32) {
        float cosv = sred[t][0] / (fmaxf(sqrtf(sred[t][1]), 1e-8f) * sqrtf(2048.0f));
        strenL[t] = 1.0f / (1.0f + expf(-cosv));
    }
    __syncthreads();

    #pragma unroll
    for (int nt = 0; nt < 2; ++nt) {
        #pragma unroll
        for (int j = 0; j < 4; ++j) {
            int rloc = wm * 16 + lg * 4 + j;
            int col = d0 + wn * 32 + nt * 16 + lr;
            size_t gi = (size_t)(row0 + rloc) * DD + col;
            out[gi] = mixed[gi] + (acc[nt][j] + bfh[col]) * strenL[rloc];
        }
    }
}

extern "C" void kernel_launch(void* const* d_in, const int* in_sizes, int n_in,
                              void* d_out, int out_size, void* d_ws, size_t ws_size,
                              hipStream_t stream) {
    const float* states    = (const float*)d_in[0];
    const float* actions   = (const float*)d_in[1];
    const float* mem       = (const float*)d_in[2];
    const float* Wq        = (const float*)d_in[3];
    const float* bq        = (const float*)d_in[4];
    const float* Wk        = (const float*)d_in[5];
    const float* bk        = (const float*)d_in[6];
    const float* log_temp  = (const float*)d_in[7];
    const float* Wc        = (const float*)d_in[8];
    const float* bc        = (const float*)d_in[9];
    const float* temp_coal = (const float*)d_in[10];
    const float* W2h       = (const float*)d_in[11];
    const float* b2h       = (const float*)d_in[12];
    const float* Wfh       = (const float*)d_in[13];
    const float* bfh       = (const float*)d_in[14];
    const float* keys      = (const float*)d_in[15];
    const float* pos_codes = (const float*)d_in[16];
    const int*   step      = (const int*)d_in[17];
    float* out = (float*)d_out;

    float* ws = (float*)d_ws;
    float* mixed    = ws;                                    // 2,097,152 f32
    short* W2hT_hi  = (short*)(mixed + 2097152);             // 524288 shorts
    short* WfhT_hi  = W2hT_hi + 524288;
    unsigned short* qbits = (unsigned short*)(WfhT_hi + 524288);  // 1,048,576 u16
    float* Q        = (float*)(qbits + 1048576);             // 524288 f32
    float* K        = Q + 524288;
    float* incoming = K + 524288;                            // 2,097,152 f32
    short* pn_bf    = (short*)(incoming + 2097152);          // 524288 shorts

    head_kernel<<<1536, 256, 0, stream>>>(actions, Wq, bq, Wk, bk, Wc, bc, W2h, Wfh,
                                          Q, K, pn_bf, W2hT_hi, WfhT_hi);
    attn_fused_kernel<<<BATCH * NN / 8, 512, 0, stream>>>(Q, K, log_temp, states, incoming);
    coal_kernel<<<BATCH * (NN / 32) * 2, 256, 0, stream>>>(pn_bf, incoming, temp_coal, mixed);
    hdcA_kernel<<<(BATCH * NN / 32) * 8, 256, 0, stream>>>(mixed, W2hT_hi, b2h, qbits);
    hdcB_kernel<<<(BATCH * NN / 32) * 2, 512, 0, stream>>>(mem, qbits, pos_codes, step,
                                                           WfhT_hi, bfh, keys, mixed, out);
}